// Round 2
// 195.425 us; speedup vs baseline: 1.0218x; 1.0218x over previous
//
#include <hip/hip_runtime.h>

typedef _Float16 half_t;
typedef _Float16 half8 __attribute__((ext_vector_type(8)));
typedef _Float16 half4_t __attribute__((ext_vector_type(4)));
typedef _Float16 half2_t __attribute__((ext_vector_type(2)));
typedef float floatx4 __attribute__((ext_vector_type(4)));
typedef float floatx16 __attribute__((ext_vector_type(16)));

#define B_SZ 2
#define SEQ 2048
#define DIM_ 1024
#define NH 16
#define DH 64
#define ROWS (B_SZ * SEQ)   // 4096

// async global->LDS, 16B per lane; LDS dest = wave-uniform base + lane*16
__device__ __forceinline__ void gl2lds16(const void* g, void* l) {
  __builtin_amdgcn_global_load_lds((const __attribute__((address_space(1))) unsigned int*)g,
                                   (__attribute__((address_space(3))) unsigned int*)l, 16, 0, 0);
}

// exp2 (single v_exp_f32; log2(e) folded into q scale at GEMM epilogue)
__device__ __forceinline__ float fexp2(float x) {
#if __has_builtin(__builtin_amdgcn_exp2f)
  return __builtin_amdgcn_exp2f(x);
#else
  return __expf(x * 0.6931471805599453f);  // exp((log2e*S)*ln2) == exp(S)
#endif
}

__device__ __forceinline__ half4_t pack4(float p0, float p1, float p2, float p3) {
#if __has_builtin(__builtin_amdgcn_cvt_pkrtz)
  half2_t lo = __builtin_bit_cast(half2_t, __builtin_amdgcn_cvt_pkrtz(p0, p1));
  half2_t hi = __builtin_bit_cast(half2_t, __builtin_amdgcn_cvt_pkrtz(p2, p3));
  half4_t r;
  r.x = lo.x; r.y = lo.y; r.z = hi.x; r.w = hi.y;
  return r;
#else
  half4_t r;
  r.x = (half_t)p0; r.y = (half_t)p1; r.z = (half_t)p2; r.w = (half_t)p3;
  return r;
#endif
}

// one kernel converts x, w_qkv, w_proj (contiguous in ws) fp32->fp16
__global__ __launch_bounds__(256) void convert_all(const float4* __restrict__ x,
                                                   const float4* __restrict__ wq,
                                                   const float4* __restrict__ wp,
                                                   half4_t* __restrict__ dst,
                                                   int nx, int nq, int np) {
  int i = blockIdx.x * blockDim.x + threadIdx.x;
  float4 v;
  if (i < nx) v = x[i];
  else if (i < nx + nq) v = wq[i - nx];
  else if (i < nx + nq + np) v = wp[i - nx - nq];
  else return;
  half4_t h;
  h.x = (half_t)v.x; h.y = (half_t)v.y; h.z = (half_t)v.z; h.w = (half_t)v.w;
  dst[i] = h;
}

// C = A[4096][1024] @ Bt[N][1024]^T. 32x32x16 MFMA, BK=64, 128xBN tile, 4 waves.
// MODE 0 (BN=128): qkv epilogue. MODE 1 (BN=64): proj fp32 out.
template <int MODE, int BN>
__global__ __launch_bounds__(256) void gemm32(const half_t* __restrict__ A,
                                              const half_t* __restrict__ Bt,
                                              half_t* __restrict__ q16,
                                              half_t* __restrict__ k16,
                                              half_t* __restrict__ vT16,
                                              float* __restrict__ outp) {
  constexpr int K = 1024;
  constexpr int NT = BN / 64;  // 32x32 n-tiles per wave
  __shared__ __align__(16) half_t a_lds[128 * 64];
  __shared__ __align__(16) half_t b_lds[BN * 64];
  const int t = threadIdx.x;
  const int wave = t >> 6, lane = t & 63;
  const int l31 = lane & 31, hw = lane >> 5;
  const int wm = wave >> 1, wn = wave & 1;
  const int row0 = blockIdx.y * 128, col0 = blockIdx.x * BN;

  floatx16 acc[2][NT];
#pragma unroll
  for (int i = 0; i < 2; ++i)
#pragma unroll
    for (int j = 0; j < NT; ++j)
#pragma unroll
      for (int r = 0; r < 16; ++r) acc[i][j][r] = 0.f;

  for (int k0 = 0; k0 < K; k0 += 64) {
    // A: 128 rows x 8 chunks(16B) = 1024 segs, 4/thread
#pragma unroll
    for (int hi = 0; hi < 4; ++hi) {
      int s = t + hi * 256;
      int row = s >> 3, c = s & 7;
      int sc = c ^ (row & 7);
      gl2lds16(A + (size_t)(row0 + row) * K + (k0 + sc * 8), a_lds + (wave * 64 + hi * 256) * 8);
    }
    // B: BN rows x 8 chunks
#pragma unroll
    for (int hi = 0; hi < BN / 32; ++hi) {
      int s = t + hi * 256;
      int row = s >> 3, c = s & 7;
      int sc = c ^ (row & 7);
      gl2lds16(Bt + (size_t)(col0 + row) * K + (k0 + sc * 8), b_lds + (wave * 64 + hi * 256) * 8);
    }
    __syncthreads();
    half8 af[2][4], bf[NT][4];
#pragma unroll
    for (int mt = 0; mt < 2; ++mt) {
      int row = wm * 64 + mt * 32 + l31;
#pragma unroll
      for (int kf = 0; kf < 4; ++kf)
        af[mt][kf] = *(const half8*)(a_lds + row * 64 + ((kf * 2 + hw) ^ (row & 7)) * 8);
    }
#pragma unroll
    for (int nt = 0; nt < NT; ++nt) {
      int row = wn * (BN / 2) + nt * 32 + l31;
#pragma unroll
      for (int kf = 0; kf < 4; ++kf)
        bf[nt][kf] = *(const half8*)(b_lds + row * 64 + ((kf * 2 + hw) ^ (row & 7)) * 8);
    }
#pragma unroll
    for (int kf = 0; kf < 4; ++kf)
#pragma unroll
      for (int mt = 0; mt < 2; ++mt)
#pragma unroll
        for (int nt = 0; nt < NT; ++nt)
          acc[mt][nt] =
              __builtin_amdgcn_mfma_f32_32x32x16_f16(af[mt][kf], bf[nt][kf], acc[mt][nt], 0, 0, 0);
    __syncthreads();
  }

  // C/D 32x32 mapping: col = lane&31, row = (r&3) + 8*(r>>2) + 4*(lane>>5)
  if (MODE == 0) {
    const int which = col0 >> 10;
#pragma unroll
    for (int mt = 0; mt < 2; ++mt)
#pragma unroll
      for (int nt = 0; nt < NT; ++nt) {
        int growb = row0 + wm * 64 + mt * 32;
        int gcol = col0 + wn * (BN / 2) + nt * 32 + l31;
        int hc = gcol & 1023, h = hc >> 6, d = hc & 63;
        if (which == 2) {
#pragma unroll
          for (int rq = 0; rq < 4; ++rq) {
            int grow = growb + 8 * rq + 4 * hw;
            int b = grow >> 11, n0 = grow & 2047;
            int bh = b * NH + h;
            half4_t h4;
            h4.x = (half_t)acc[mt][nt][rq * 4 + 0];
            h4.y = (half_t)acc[mt][nt][rq * 4 + 1];
            h4.z = (half_t)acc[mt][nt][rq * 4 + 2];
            h4.w = (half_t)acc[mt][nt][rq * 4 + 3];
            *(half4_t*)(vT16 + ((size_t)bh * DH + d) * SEQ + n0) = h4;
          }
        } else {
#pragma unroll
          for (int r = 0; r < 16; ++r) {
            int grow = growb + (r & 3) + 8 * (r >> 2) + 4 * hw;
            int b = grow >> 11, n = grow & 2047;
            int bh = b * NH + h;
            float v = acc[mt][nt][r];
            if (which == 0)
              q16[((size_t)bh * SEQ + n) * DH + d] =
                  (half_t)(v * 0.1803368801111204f);  // fold SCALE * log2(e)
            else
              k16[((size_t)bh * SEQ + n) * DH + d] = (half_t)v;
          }
        }
      }
  } else {
#pragma unroll
    for (int mt = 0; mt < 2; ++mt)
#pragma unroll
      for (int nt = 0; nt < NT; ++nt) {
        int growb = row0 + wm * 64 + mt * 32;
        int gcol = col0 + wn * (BN / 2) + nt * 32 + l31;
#pragma unroll
        for (int r = 0; r < 16; ++r) {
          int grow = growb + (r & 3) + 8 * (r >> 2) + 4 * hw;
          outp[(size_t)grow * DIM_ + gcol] = acc[mt][nt][r];
        }
      }
  }
}

// Flash attention pass 1, j-split 2-way. Block = (bh, 256 q-rows, j-half).
// 4 waves x 64 q-rows (4 m-tiles): halves LDS reads + barriers per FLOP vs
// 32 q/wave. S^T trick (P^T in regs feeds K=16 PV MFMA). psum computed by an
// extra ones-column MFMA (P @ 1) instead of VALU adds + shuffles.
// Writes unnormalized O (fp16) + psum (fp32).
__global__ __launch_bounds__(256) void attn_p1(const half_t* __restrict__ q16,
                                               const half_t* __restrict__ k16,
                                               const half_t* __restrict__ vT16,
                                               half_t* __restrict__ opart,
                                               float* __restrict__ psums) {
  __shared__ __align__(16) half_t k_lds[2][64 * 64];  // [j][d]
  __shared__ __align__(16) half_t v_lds[2][64 * 64];  // vT: [d][j]

  const int t = threadIdx.x;
  const int wave = t >> 6, lane = t & 63;
  const int l15 = lane & 15, quad = lane >> 4;
  const int blk = blockIdx.x;
  const int js = blk & 1, qt = (blk >> 1) & 7, bh = blk >> 4;
  const half_t* qp = q16 + (size_t)bh * SEQ * DH;
  const half_t* kp = k16 + (size_t)bh * SEQ * DH;
  const half_t* vp = vT16 + (size_t)bh * DH * SEQ;
  const int q0w = qt * 256 + wave * 64;
  const int jbase = js * 1024;

  // staging offsets: 512 segs of 16B (64 rows x 8 chunks), chunk XOR row&7
  const int s0 = t, s1 = t + 256;
  const int r0_ = s0 >> 3, c0_ = (s0 & 7) ^ (r0_ & 7);
  const int r1_ = s1 >> 3, c1_ = (s1 & 7) ^ (r1_ & 7);

  // Q fragments, B-operand layout: lane l15 = q-row, k = kf*32 + quad*8 + i
  half8 qf[4][2];
#pragma unroll
  for (int mi = 0; mi < 4; ++mi)
#pragma unroll
    for (int kf = 0; kf < 2; ++kf)
      qf[mi][kf] = *(const half8*)(qp + (size_t)(q0w + mi * 16 + l15) * DH + kf * 32 + quad * 8);

  const floatx4 z4 = {0.f, 0.f, 0.f, 0.f};
  floatx4 o[4][4];   // [mi][d-tile], C/D: row=q(quad*4+r), col=d(l15)
  floatx4 oex[4];    // psum = P @ ones; row=q(quad*4+r), all cols equal
#pragma unroll
  for (int mi = 0; mi < 4; ++mi) {
    oex[mi] = z4;
#pragma unroll
    for (int i = 0; i < 4; ++i) o[mi][i] = z4;
  }
  half4_t vones;
  vones.x = (half_t)1.f; vones.y = (half_t)1.f; vones.z = (half_t)1.f; vones.w = (half_t)1.f;

  // prologue: stage tile jbase into buffer 0
  gl2lds16(kp + (size_t)(jbase + r0_) * DH + c0_ * 8, &k_lds[0][(wave * 64) * 8]);
  gl2lds16(vp + (size_t)r0_ * SEQ + jbase + c0_ * 8, &v_lds[0][(wave * 64) * 8]);
  gl2lds16(kp + (size_t)(jbase + r1_) * DH + c1_ * 8, &k_lds[0][(wave * 64 + 256) * 8]);
  gl2lds16(vp + (size_t)r1_ * SEQ + jbase + c1_ * 8, &v_lds[0][(wave * 64 + 256) * 8]);

  int cur = 0;
  for (int jt = 0; jt < 16; ++jt) {
    __syncthreads();  // publishes buf[cur], protects buf[cur^1]

    if (jt + 1 < 16) {
      const int j0 = jbase + (jt + 1) * 64, nb = cur ^ 1;
      gl2lds16(kp + (size_t)(j0 + r0_) * DH + c0_ * 8, &k_lds[nb][(wave * 64) * 8]);
      gl2lds16(vp + (size_t)r0_ * SEQ + j0 + c0_ * 8, &v_lds[nb][(wave * 64) * 8]);
      gl2lds16(kp + (size_t)(j0 + r1_) * DH + c1_ * 8, &k_lds[nb][(wave * 64 + 256) * 8]);
      gl2lds16(vp + (size_t)r1_ * SEQ + j0 + c1_ * 8, &v_lds[nb][(wave * 64 + 256) * 8]);
    }

    const half_t* kl = k_lds[cur];
    const half_t* vl = v_lds[cur];

    // S^T[j][q] per nt, immediately exp2 -> P^T K=16 A-frags (k = quad*4+r = j)
    half4_t pf[4][4];  // [mi][nt]
#pragma unroll
    for (int nt = 0; nt < 4; ++nt) {
      const int row = nt * 16 + l15;  // j-row
      half8 kb0 = *(const half8*)(kl + row * 64 + ((0 | quad) ^ (row & 7)) * 8);
      half8 kb1 = *(const half8*)(kl + row * 64 + ((4 | quad) ^ (row & 7)) * 8);
      floatx4 st[4];
      __builtin_amdgcn_s_setprio(1);
#pragma unroll
      for (int mi = 0; mi < 4; ++mi)
        st[mi] = __builtin_amdgcn_mfma_f32_16x16x32_f16(kb0, qf[mi][0], z4, 0, 0, 0);
#pragma unroll
      for (int mi = 0; mi < 4; ++mi)
        st[mi] = __builtin_amdgcn_mfma_f32_16x16x32_f16(kb1, qf[mi][1], st[mi], 0, 0, 0);
      __builtin_amdgcn_s_setprio(0);
#pragma unroll
      for (int mi = 0; mi < 4; ++mi) {
        float p0 = fexp2(st[mi][0]);
        float p1 = fexp2(st[mi][1]);
        float p2 = fexp2(st[mi][2]);
        float p3 = fexp2(st[mi][3]);
        pf[mi][nt] = pack4(p0, p1, p2, p3);
      }
    }

    // O[q][d] += P@V; B-frag V[j=jt2*16+quad*4+i][d=dt*16+l15] from vT LDS
    __builtin_amdgcn_s_setprio(1);
#pragma unroll
    for (int jt2 = 0; jt2 < 4; ++jt2) {
#pragma unroll
      for (int dt = 0; dt < 4; ++dt) {
        int row = dt * 16 + l15;
        int ch = (jt2 * 2 + (quad >> 1)) ^ (l15 & 7);
        half4_t vb = *(const half4_t*)(vl + row * 64 + ch * 8 + (quad & 1) * 4);
#pragma unroll
        for (int mi = 0; mi < 4; ++mi)
          o[mi][dt] = __builtin_amdgcn_mfma_f32_16x16x16f16(pf[mi][jt2], vb, o[mi][dt], 0, 0, 0);
      }
#pragma unroll
      for (int mi = 0; mi < 4; ++mi)
        oex[mi] = __builtin_amdgcn_mfma_f32_16x16x16f16(pf[mi][jt2], vones, oex[mi], 0, 0, 0);
    }
    __builtin_amdgcn_s_setprio(0);
    cur ^= 1;
  }

  // psums: oex[mi][r] holds sum_j P for q = q0w + mi*16 + quad*4 + r (all l15 equal)
  if (l15 == 0) {
#pragma unroll
    for (int mi = 0; mi < 4; ++mi)
#pragma unroll
      for (int r = 0; r < 4; ++r)
        psums[((size_t)(js * 32 + bh)) * SEQ + q0w + mi * 16 + quad * 4 + r] = oex[mi][r];
  }

  // unnormalized O -> fp16 partials
#pragma unroll
  for (int mi = 0; mi < 4; ++mi)
#pragma unroll
    for (int r = 0; r < 4; ++r) {
      int n = q0w + mi * 16 + quad * 4 + r;
      size_t base = ((size_t)(js * 32 + bh) * SEQ + n) * DH;
#pragma unroll
      for (int dt = 0; dt < 4; ++dt)
        opart[base + dt * 16 + l15] = (half_t)o[mi][dt][r];
    }
}

// combine: out = (O0+O1) * softmax(head_w)[h] / (ps0+ps1), write fp16 attn16
__global__ __launch_bounds__(256) void combine(const half_t* __restrict__ opart,
                                               const float* __restrict__ psums,
                                               const float* __restrict__ head_w,
                                               half_t* __restrict__ attn16) {
  int idx = blockIdx.x * blockDim.x + threadIdx.x;  // 1M threads, 4 d each
  int d4 = idx & 15, n = (idx >> 4) & 2047, bh = idx >> 15;
  int h = bh & 15, b = bh >> 4;
  const size_t jstr = (size_t)32 * SEQ * DH;
  size_t off = ((size_t)bh * SEQ + n) * DH + d4 * 4;
  half4_t o0 = *(const half4_t*)(opart + off);
  half4_t o1 = *(const half4_t*)(opart + jstr + off);
  float ps = psums[(size_t)bh * SEQ + n] + psums[(size_t)32 * SEQ + (size_t)bh * SEQ + n];

  float mw = head_w[0];
#pragma unroll
  for (int i = 1; i < NH; ++i) mw = fmaxf(mw, head_w[i]);
  float sw = 0.f;
#pragma unroll
  for (int i = 0; i < NH; ++i) sw += __expf(head_w[i] - mw);
  float hwv = __expf(head_w[h] - mw) / sw;

  float scl = hwv / ps;
  half4_t r;
  r.x = (half_t)(((float)o0.x + (float)o1.x) * scl);
  r.y = (half_t)(((float)o0.y + (float)o1.y) * scl);
  r.z = (half_t)(((float)o0.z + (float)o1.z) * scl);
  r.w = (half_t)(((float)o0.w + (float)o1.w) * scl);
  *(half4_t*)(attn16 + ((size_t)(b * SEQ + n)) * DIM_ + h * DH + d4 * 4) = r;
}

extern "C" void kernel_launch(void* const* d_in, const int* in_sizes, int n_in,
                              void* d_out, int out_size, void* d_ws, size_t ws_size,
                              hipStream_t stream) {
  const float* x = (const float*)d_in[0];
  const float* w_qkv = (const float*)d_in[1];
  const float* w_proj = (const float*)d_in[2];
  const float* head_w = (const float*)d_in[3];
  float* out = (float*)d_out;

  half_t* x16 = (half_t*)d_ws;                          // 4096*1024
  half_t* wq16 = x16 + (size_t)ROWS * DIM_;             // 3072*1024
  half_t* wp16 = wq16 + (size_t)3 * DIM_ * DIM_;        // 1024*1024
  half_t* q16 = wp16 + (size_t)DIM_ * DIM_;             // [B,H,N,Dh]  (scaled by 0.125*log2e)
  half_t* k16 = q16 + (size_t)ROWS * DIM_;              // [B,H,N,Dh]
  half_t* vT16 = k16 + (size_t)ROWS * DIM_;             // [B,H,Dh,N]
  half_t* attn16 = vT16 + (size_t)ROWS * DIM_;          // [B*N, DIM]
  half_t* opart = attn16 + (size_t)ROWS * DIM_;         // [2][32][2048][64] fp16
  float* psums = (float*)(opart + (size_t)2 * 32 * SEQ * DH);  // [2][32][2048] f32

  const int nx = ROWS * DIM_ / 4, nq = 3 * DIM_ * DIM_ / 4, np = DIM_ * DIM_ / 4;
  convert_all<<<(nx + nq + np) / 256, 256, 0, stream>>>((const float4*)x, (const float4*)w_qkv,
                                                        (const float4*)w_proj, (half4_t*)x16,
                                                        nx, nq, np);

  gemm32<0, 128><<<dim3(24, 32), 256, 0, stream>>>(x16, wq16, q16, k16, vT16, nullptr);
  attn_p1<<<32 * 8 * 2, 256, 0, stream>>>(q16, k16, vT16, opart, psums);
  combine<<<(32 * SEQ * DH / 4) / 256, 256, 0, stream>>>(opart, psums, head_w, attn16);
  gemm32<1, 64><<<dim3(16, 32), 256, 0, stream>>>(attn16, wp16, nullptr, nullptr, nullptr, out);
}

// Round 3
// 191.522 us; speedup vs baseline: 1.0426x; 1.0204x over previous
//
#include <hip/hip_runtime.h>

typedef _Float16 half_t;
typedef _Float16 half8 __attribute__((ext_vector_type(8)));
typedef _Float16 half4_t __attribute__((ext_vector_type(4)));
typedef _Float16 half2_t __attribute__((ext_vector_type(2)));
typedef float floatx4 __attribute__((ext_vector_type(4)));
typedef float floatx16 __attribute__((ext_vector_type(16)));

#define B_SZ 2
#define SEQ 2048
#define DIM_ 1024
#define NH 16
#define DH 64
#define ROWS (B_SZ * SEQ)   // 4096
#define NJS 4               // j-split ways (occupancy: 32*8*NJS blocks)

// async global->LDS, 16B per lane; LDS dest = wave-uniform base + lane*16
__device__ __forceinline__ void gl2lds16(const void* g, void* l) {
  __builtin_amdgcn_global_load_lds((const __attribute__((address_space(1))) unsigned int*)g,
                                   (__attribute__((address_space(3))) unsigned int*)l, 16, 0, 0);
}

// exp2 (single v_exp_f32; log2(e) folded into q scale at GEMM epilogue)
__device__ __forceinline__ float fexp2(float x) {
#if __has_builtin(__builtin_amdgcn_exp2f)
  return __builtin_amdgcn_exp2f(x);
#else
  return __expf(x * 0.6931471805599453f);  // exp((log2e*S)*ln2) == exp(S)
#endif
}

__device__ __forceinline__ half4_t pack4(float p0, float p1, float p2, float p3) {
#if __has_builtin(__builtin_amdgcn_cvt_pkrtz)
  half2_t lo = __builtin_bit_cast(half2_t, __builtin_amdgcn_cvt_pkrtz(p0, p1));
  half2_t hi = __builtin_bit_cast(half2_t, __builtin_amdgcn_cvt_pkrtz(p2, p3));
  half4_t r;
  r.x = lo.x; r.y = lo.y; r.z = hi.x; r.w = hi.y;
  return r;
#else
  half4_t r;
  r.x = (half_t)p0; r.y = (half_t)p1; r.z = (half_t)p2; r.w = (half_t)p3;
  return r;
#endif
}

// one kernel converts x, w_qkv, w_proj (contiguous in ws) fp32->fp16
__global__ __launch_bounds__(256) void convert_all(const float4* __restrict__ x,
                                                   const float4* __restrict__ wq,
                                                   const float4* __restrict__ wp,
                                                   half4_t* __restrict__ dst,
                                                   int nx, int nq, int np) {
  int i = blockIdx.x * blockDim.x + threadIdx.x;
  float4 v;
  if (i < nx) v = x[i];
  else if (i < nx + nq) v = wq[i - nx];
  else if (i < nx + nq + np) v = wp[i - nx - nq];
  else return;
  half4_t h;
  h.x = (half_t)v.x; h.y = (half_t)v.y; h.z = (half_t)v.z; h.w = (half_t)v.w;
  dst[i] = h;
}

// C = A[4096][1024] @ Bt[N][1024]^T. 32x32x16 MFMA, BK=64, 128xBN tile, 4 waves.
// MODE 0 (BN=128): qkv epilogue. MODE 1 (BN=64): proj fp32 out.
template <int MODE, int BN>
__global__ __launch_bounds__(256) void gemm32(const half_t* __restrict__ A,
                                              const half_t* __restrict__ Bt,
                                              half_t* __restrict__ q16,
                                              half_t* __restrict__ k16,
                                              half_t* __restrict__ vT16,
                                              float* __restrict__ outp) {
  constexpr int K = 1024;
  constexpr int NT = BN / 64;  // 32x32 n-tiles per wave
  __shared__ __align__(16) half_t a_lds[128 * 64];
  __shared__ __align__(16) half_t b_lds[BN * 64];
  const int t = threadIdx.x;
  const int wave = t >> 6, lane = t & 63;
  const int l31 = lane & 31, hw = lane >> 5;
  const int wm = wave >> 1, wn = wave & 1;
  const int row0 = blockIdx.y * 128, col0 = blockIdx.x * BN;

  floatx16 acc[2][NT];
#pragma unroll
  for (int i = 0; i < 2; ++i)
#pragma unroll
    for (int j = 0; j < NT; ++j)
#pragma unroll
      for (int r = 0; r < 16; ++r) acc[i][j][r] = 0.f;

  for (int k0 = 0; k0 < K; k0 += 64) {
    // A: 128 rows x 8 chunks(16B) = 1024 segs, 4/thread
#pragma unroll
    for (int hi = 0; hi < 4; ++hi) {
      int s = t + hi * 256;
      int row = s >> 3, c = s & 7;
      int sc = c ^ (row & 7);
      gl2lds16(A + (size_t)(row0 + row) * K + (k0 + sc * 8), a_lds + (wave * 64 + hi * 256) * 8);
    }
    // B: BN rows x 8 chunks
#pragma unroll
    for (int hi = 0; hi < BN / 32; ++hi) {
      int s = t + hi * 256;
      int row = s >> 3, c = s & 7;
      int sc = c ^ (row & 7);
      gl2lds16(Bt + (size_t)(col0 + row) * K + (k0 + sc * 8), b_lds + (wave * 64 + hi * 256) * 8);
    }
    __syncthreads();
    half8 af[2][4], bf[NT][4];
#pragma unroll
    for (int mt = 0; mt < 2; ++mt) {
      int row = wm * 64 + mt * 32 + l31;
#pragma unroll
      for (int kf = 0; kf < 4; ++kf)
        af[mt][kf] = *(const half8*)(a_lds + row * 64 + ((kf * 2 + hw) ^ (row & 7)) * 8);
    }
#pragma unroll
    for (int nt = 0; nt < NT; ++nt) {
      int row = wn * (BN / 2) + nt * 32 + l31;
#pragma unroll
      for (int kf = 0; kf < 4; ++kf)
        bf[nt][kf] = *(const half8*)(b_lds + row * 64 + ((kf * 2 + hw) ^ (row & 7)) * 8);
    }
#pragma unroll
    for (int kf = 0; kf < 4; ++kf)
#pragma unroll
      for (int mt = 0; mt < 2; ++mt)
#pragma unroll
        for (int nt = 0; nt < NT; ++nt)
          acc[mt][nt] =
              __builtin_amdgcn_mfma_f32_32x32x16_f16(af[mt][kf], bf[nt][kf], acc[mt][nt], 0, 0, 0);
    __syncthreads();
  }

  // C/D 32x32 mapping: col = lane&31, row = (r&3) + 8*(r>>2) + 4*(lane>>5)
  if (MODE == 0) {
    const int which = col0 >> 10;
#pragma unroll
    for (int mt = 0; mt < 2; ++mt)
#pragma unroll
      for (int nt = 0; nt < NT; ++nt) {
        int growb = row0 + wm * 64 + mt * 32;
        int gcol = col0 + wn * (BN / 2) + nt * 32 + l31;
        int hc = gcol & 1023, h = hc >> 6, d = hc & 63;
        if (which == 2) {
#pragma unroll
          for (int rq = 0; rq < 4; ++rq) {
            int grow = growb + 8 * rq + 4 * hw;
            int b = grow >> 11, n0 = grow & 2047;
            int bh = b * NH + h;
            half4_t h4;
            h4.x = (half_t)acc[mt][nt][rq * 4 + 0];
            h4.y = (half_t)acc[mt][nt][rq * 4 + 1];
            h4.z = (half_t)acc[mt][nt][rq * 4 + 2];
            h4.w = (half_t)acc[mt][nt][rq * 4 + 3];
            *(half4_t*)(vT16 + ((size_t)bh * DH + d) * SEQ + n0) = h4;
          }
        } else {
#pragma unroll
          for (int r = 0; r < 16; ++r) {
            int grow = growb + (r & 3) + 8 * (r >> 2) + 4 * hw;
            int b = grow >> 11, n = grow & 2047;
            int bh = b * NH + h;
            float v = acc[mt][nt][r];
            if (which == 0)
              q16[((size_t)bh * SEQ + n) * DH + d] =
                  (half_t)(v * 0.1803368801111204f);  // fold SCALE * log2(e)
            else
              k16[((size_t)bh * SEQ + n) * DH + d] = (half_t)v;
          }
        }
      }
  } else {
#pragma unroll
    for (int mt = 0; mt < 2; ++mt)
#pragma unroll
      for (int nt = 0; nt < NT; ++nt) {
        int growb = row0 + wm * 64 + mt * 32;
        int gcol = col0 + wn * (BN / 2) + nt * 32 + l31;
#pragma unroll
        for (int r = 0; r < 16; ++r) {
          int grow = growb + (r & 3) + 8 * (r >> 2) + 4 * hw;
          outp[(size_t)grow * DIM_ + gcol] = acc[mt][nt][r];
        }
      }
  }
}

// Flash attention pass 1, j-split NJS-way. Block = (bh, 256 q-rows, j-slice).
// 4 waves x 64 q-rows (4 m-tiles). Grid 32*8*NJS=1024 -> 4 blocks/CU (16
// waves/CU) to hide the ds_read->MFMA->exp->MFMA chain latency. S^T trick
// (P^T in regs feeds K=16 PV MFMA). psum via ones-column MFMA (P @ 1).
// Writes unnormalized O (fp16) + psum (fp32) per j-slice.
__global__ __launch_bounds__(256) void attn_p1(const half_t* __restrict__ q16,
                                               const half_t* __restrict__ k16,
                                               const half_t* __restrict__ vT16,
                                               half_t* __restrict__ opart,
                                               float* __restrict__ psums) {
  __shared__ __align__(16) half_t k_lds[2][64 * 64];  // [j][d]
  __shared__ __align__(16) half_t v_lds[2][64 * 64];  // vT: [d][j]

  const int t = threadIdx.x;
  const int wave = t >> 6, lane = t & 63;
  const int l15 = lane & 15, quad = lane >> 4;
  const int blk = blockIdx.x;
  const int js = blk & (NJS - 1), qt = (blk >> 2) & 7, bh = blk >> 5;
  const half_t* qp = q16 + (size_t)bh * SEQ * DH;
  const half_t* kp = k16 + (size_t)bh * SEQ * DH;
  const half_t* vp = vT16 + (size_t)bh * DH * SEQ;
  const int q0w = qt * 256 + wave * 64;
  const int jbase = js * (SEQ / NJS);      // 512-wide j slice
  constexpr int NJT = (SEQ / NJS) / 64;    // 8 tiles of 64

  // staging offsets: 512 segs of 16B (64 rows x 8 chunks), chunk XOR row&7
  const int s0 = t, s1 = t + 256;
  const int r0_ = s0 >> 3, c0_ = (s0 & 7) ^ (r0_ & 7);
  const int r1_ = s1 >> 3, c1_ = (s1 & 7) ^ (r1_ & 7);

  // Q fragments, B-operand layout: lane l15 = q-row, k = kf*32 + quad*8 + i
  half8 qf[4][2];
#pragma unroll
  for (int mi = 0; mi < 4; ++mi)
#pragma unroll
    for (int kf = 0; kf < 2; ++kf)
      qf[mi][kf] = *(const half8*)(qp + (size_t)(q0w + mi * 16 + l15) * DH + kf * 32 + quad * 8);

  const floatx4 z4 = {0.f, 0.f, 0.f, 0.f};
  floatx4 o[4][4];   // [mi][d-tile], C/D: row=q(quad*4+r), col=d(l15)
  floatx4 oex[4];    // psum = P @ ones; row=q(quad*4+r), all cols equal
#pragma unroll
  for (int mi = 0; mi < 4; ++mi) {
    oex[mi] = z4;
#pragma unroll
    for (int i = 0; i < 4; ++i) o[mi][i] = z4;
  }
  half4_t vones;
  vones.x = (half_t)1.f; vones.y = (half_t)1.f; vones.z = (half_t)1.f; vones.w = (half_t)1.f;

  // prologue: stage tile jbase into buffer 0
  gl2lds16(kp + (size_t)(jbase + r0_) * DH + c0_ * 8, &k_lds[0][(wave * 64) * 8]);
  gl2lds16(vp + (size_t)r0_ * SEQ + jbase + c0_ * 8, &v_lds[0][(wave * 64) * 8]);
  gl2lds16(kp + (size_t)(jbase + r1_) * DH + c1_ * 8, &k_lds[0][(wave * 64 + 256) * 8]);
  gl2lds16(vp + (size_t)r1_ * SEQ + jbase + c1_ * 8, &v_lds[0][(wave * 64 + 256) * 8]);

  int cur = 0;
  for (int jt = 0; jt < NJT; ++jt) {
    __syncthreads();  // publishes buf[cur], protects buf[cur^1]

    if (jt + 1 < NJT) {
      const int j0 = jbase + (jt + 1) * 64, nb = cur ^ 1;
      gl2lds16(kp + (size_t)(j0 + r0_) * DH + c0_ * 8, &k_lds[nb][(wave * 64) * 8]);
      gl2lds16(vp + (size_t)r0_ * SEQ + j0 + c0_ * 8, &v_lds[nb][(wave * 64) * 8]);
      gl2lds16(kp + (size_t)(j0 + r1_) * DH + c1_ * 8, &k_lds[nb][(wave * 64 + 256) * 8]);
      gl2lds16(vp + (size_t)r1_ * SEQ + j0 + c1_ * 8, &v_lds[nb][(wave * 64 + 256) * 8]);
    }

    const half_t* kl = k_lds[cur];
    const half_t* vl = v_lds[cur];

    // S^T[j][q] per nt, immediately exp2 -> P^T K=16 A-frags (k = quad*4+r = j)
    half4_t pf[4][4];  // [mi][nt]
#pragma unroll
    for (int nt = 0; nt < 4; ++nt) {
      const int row = nt * 16 + l15;  // j-row
      half8 kb0 = *(const half8*)(kl + row * 64 + ((0 | quad) ^ (row & 7)) * 8);
      half8 kb1 = *(const half8*)(kl + row * 64 + ((4 | quad) ^ (row & 7)) * 8);
      floatx4 st[4];
      __builtin_amdgcn_s_setprio(1);
#pragma unroll
      for (int mi = 0; mi < 4; ++mi)
        st[mi] = __builtin_amdgcn_mfma_f32_16x16x32_f16(kb0, qf[mi][0], z4, 0, 0, 0);
#pragma unroll
      for (int mi = 0; mi < 4; ++mi)
        st[mi] = __builtin_amdgcn_mfma_f32_16x16x32_f16(kb1, qf[mi][1], st[mi], 0, 0, 0);
      __builtin_amdgcn_s_setprio(0);
#pragma unroll
      for (int mi = 0; mi < 4; ++mi) {
        float p0 = fexp2(st[mi][0]);
        float p1 = fexp2(st[mi][1]);
        float p2 = fexp2(st[mi][2]);
        float p3 = fexp2(st[mi][3]);
        pf[mi][nt] = pack4(p0, p1, p2, p3);
      }
    }

    // O[q][d] += P@V; B-frag V[j=jt2*16+quad*4+i][d=dt*16+l15] from vT LDS
    __builtin_amdgcn_s_setprio(1);
#pragma unroll
    for (int jt2 = 0; jt2 < 4; ++jt2) {
#pragma unroll
      for (int dt = 0; dt < 4; ++dt) {
        int row = dt * 16 + l15;
        int ch = (jt2 * 2 + (quad >> 1)) ^ (l15 & 7);
        half4_t vb = *(const half4_t*)(vl + row * 64 + ch * 8 + (quad & 1) * 4);
#pragma unroll
        for (int mi = 0; mi < 4; ++mi)
          o[mi][dt] = __builtin_amdgcn_mfma_f32_16x16x16f16(pf[mi][jt2], vb, o[mi][dt], 0, 0, 0);
      }
#pragma unroll
      for (int mi = 0; mi < 4; ++mi)
        oex[mi] = __builtin_amdgcn_mfma_f32_16x16x16f16(pf[mi][jt2], vones, oex[mi], 0, 0, 0);
    }
    __builtin_amdgcn_s_setprio(0);
    cur ^= 1;
  }

  // psums: oex[mi][r] holds sum_j P for q = q0w + mi*16 + quad*4 + r (all l15 equal)
  if (l15 == 0) {
#pragma unroll
    for (int mi = 0; mi < 4; ++mi)
#pragma unroll
      for (int r = 0; r < 4; ++r)
        psums[((size_t)(js * 32 + bh)) * SEQ + q0w + mi * 16 + quad * 4 + r] = oex[mi][r];
  }

  // unnormalized O -> fp16 partials
#pragma unroll
  for (int mi = 0; mi < 4; ++mi)
#pragma unroll
    for (int r = 0; r < 4; ++r) {
      int n = q0w + mi * 16 + quad * 4 + r;
      size_t base = ((size_t)(js * 32 + bh) * SEQ + n) * DH;
#pragma unroll
      for (int dt = 0; dt < 4; ++dt)
        opart[base + dt * 16 + l15] = (half_t)o[mi][dt][r];
    }
}

// combine: out = (sum_js O_js) * softmax(head_w)[h] / (sum_js ps_js), fp16 attn16
__global__ __launch_bounds__(256) void combine(const half_t* __restrict__ opart,
                                               const float* __restrict__ psums,
                                               const float* __restrict__ head_w,
                                               half_t* __restrict__ attn16) {
  int idx = blockIdx.x * blockDim.x + threadIdx.x;  // 1M threads, 4 d each
  int d4 = idx & 15, n = (idx >> 4) & 2047, bh = idx >> 15;
  int h = bh & 15, b = bh >> 4;
  const size_t jstr = (size_t)32 * SEQ * DH;
  size_t off = ((size_t)bh * SEQ + n) * DH + d4 * 4;

  float sx = 0.f, sy = 0.f, sz = 0.f, sw2 = 0.f, ps = 0.f;
#pragma unroll
  for (int js = 0; js < NJS; ++js) {
    half4_t ov = *(const half4_t*)(opart + js * jstr + off);
    sx += (float)ov.x; sy += (float)ov.y; sz += (float)ov.z; sw2 += (float)ov.w;
    ps += psums[(size_t)js * 32 * SEQ + (size_t)bh * SEQ + n];
  }

  float mw = head_w[0];
#pragma unroll
  for (int i = 1; i < NH; ++i) mw = fmaxf(mw, head_w[i]);
  float sw = 0.f;
#pragma unroll
  for (int i = 0; i < NH; ++i) sw += __expf(head_w[i] - mw);
  float hwv = __expf(head_w[h] - mw) / sw;

  float scl = hwv / ps;
  half4_t r;
  r.x = (half_t)(sx * scl);
  r.y = (half_t)(sy * scl);
  r.z = (half_t)(sz * scl);
  r.w = (half_t)(sw2 * scl);
  *(half4_t*)(attn16 + ((size_t)(b * SEQ + n)) * DIM_ + h * DH + d4 * 4) = r;
}

extern "C" void kernel_launch(void* const* d_in, const int* in_sizes, int n_in,
                              void* d_out, int out_size, void* d_ws, size_t ws_size,
                              hipStream_t stream) {
  const float* x = (const float*)d_in[0];
  const float* w_qkv = (const float*)d_in[1];
  const float* w_proj = (const float*)d_in[2];
  const float* head_w = (const float*)d_in[3];
  float* out = (float*)d_out;

  half_t* x16 = (half_t*)d_ws;                          // 4096*1024
  half_t* wq16 = x16 + (size_t)ROWS * DIM_;             // 3072*1024
  half_t* wp16 = wq16 + (size_t)3 * DIM_ * DIM_;        // 1024*1024
  half_t* q16 = wp16 + (size_t)DIM_ * DIM_;             // [B,H,N,Dh]  (scaled by 0.125*log2e)
  half_t* k16 = q16 + (size_t)ROWS * DIM_;              // [B,H,N,Dh]
  half_t* vT16 = k16 + (size_t)ROWS * DIM_;             // [B,H,Dh,N]
  half_t* attn16 = vT16 + (size_t)ROWS * DIM_;          // [B*N, DIM]
  half_t* opart = attn16 + (size_t)ROWS * DIM_;         // [NJS][32][2048][64] fp16
  float* psums = (float*)(opart + (size_t)NJS * 32 * SEQ * DH);  // [NJS][32][2048] f32
  // total: ~48MB fp16 bufs + 33.5MB opart + 1MB psums ~= 85MB workspace

  const int nx = ROWS * DIM_ / 4, nq = 3 * DIM_ * DIM_ / 4, np = DIM_ * DIM_ / 4;
  convert_all<<<(nx + nq + np) / 256, 256, 0, stream>>>((const float4*)x, (const float4*)w_qkv,
                                                        (const float4*)w_proj, (half4_t*)x16,
                                                        nx, nq, np);

  gemm32<0, 128><<<dim3(24, 32), 256, 0, stream>>>(x16, wq16, q16, k16, vT16, nullptr);
  attn_p1<<<32 * 8 * NJS, 256, 0, stream>>>(q16, k16, vT16, opart, psums);
  combine<<<(32 * SEQ * DH / 4) / 256, 256, 0, stream>>>(opart, psums, head_w, attn16);
  gemm32<1, 64><<<dim3(16, 32), 256, 0, stream>>>(attn16, wp16, nullptr, nullptr, nullptr, out);
}

// Round 4
// 189.451 us; speedup vs baseline: 1.0540x; 1.0109x over previous
//
#include <hip/hip_runtime.h>

typedef _Float16 half_t;
typedef _Float16 half8 __attribute__((ext_vector_type(8)));
typedef _Float16 half4_t __attribute__((ext_vector_type(4)));
typedef _Float16 half2_t __attribute__((ext_vector_type(2)));
typedef float floatx4 __attribute__((ext_vector_type(4)));
typedef float floatx16 __attribute__((ext_vector_type(16)));
typedef unsigned int uint4v __attribute__((ext_vector_type(4)));

#define B_SZ 2
#define SEQ 2048
#define DIM_ 1024
#define NH 16
#define DH 64
#define ROWS (B_SZ * SEQ)   // 4096
#define NJS 2               // j-split ways

// async global->LDS, 16B per lane; LDS dest = wave-uniform base + lane*16
__device__ __forceinline__ void gl2lds16(const void* g, void* l) {
  __builtin_amdgcn_global_load_lds((const __attribute__((address_space(1))) unsigned int*)g,
                                   (__attribute__((address_space(3))) unsigned int*)l, 16, 0, 0);
}

// exp2 (single v_exp_f32; log2(e) folded into q scale at GEMM epilogue)
__device__ __forceinline__ float fexp2(float x) {
#if __has_builtin(__builtin_amdgcn_exp2f)
  return __builtin_amdgcn_exp2f(x);
#else
  return __expf(x * 0.6931471805599453f);
#endif
}

__device__ __forceinline__ unsigned cvtpk_u32(float a, float b) {
#if __has_builtin(__builtin_amdgcn_cvt_pkrtz)
  return __builtin_bit_cast(unsigned, __builtin_amdgcn_cvt_pkrtz(a, b));
#else
  half2_t h; h.x = (half_t)a; h.y = (half_t)b;
  return __builtin_bit_cast(unsigned, h);
#endif
}

// pack 8 f32 -> half8 via v_cvt_pkrtz
__device__ __forceinline__ half8 pack8(float p0, float p1, float p2, float p3,
                                       float p4, float p5, float p6, float p7) {
  uint4v u;
  u.x = cvtpk_u32(p0, p1);
  u.y = cvtpk_u32(p2, p3);
  u.z = cvtpk_u32(p4, p5);
  u.w = cvtpk_u32(p6, p7);
  return __builtin_bit_cast(half8, u);
}

// one kernel converts x, w_qkv, w_proj (contiguous in ws) fp32->fp16
__global__ __launch_bounds__(256) void convert_all(const float4* __restrict__ x,
                                                   const float4* __restrict__ wq,
                                                   const float4* __restrict__ wp,
                                                   half4_t* __restrict__ dst,
                                                   int nx, int nq, int np) {
  int i = blockIdx.x * blockDim.x + threadIdx.x;
  float4 v;
  if (i < nx) v = x[i];
  else if (i < nx + nq) v = wq[i - nx];
  else if (i < nx + nq + np) v = wp[i - nx - nq];
  else return;
  half4_t h;
  h.x = (half_t)v.x; h.y = (half_t)v.y; h.z = (half_t)v.z; h.w = (half_t)v.w;
  dst[i] = h;
}

// C = A[4096][1024] @ Bt[N][1024]^T. 32x32x16 MFMA, BK=64, 128xBN tile, 4 waves.
// MODE 0 (BN=128): qkv epilogue. MODE 1 (BN=64): proj fp32 out.
template <int MODE, int BN>
__global__ __launch_bounds__(256) void gemm32(const half_t* __restrict__ A,
                                              const half_t* __restrict__ Bt,
                                              half_t* __restrict__ q16,
                                              half_t* __restrict__ k16,
                                              half_t* __restrict__ vT16,
                                              float* __restrict__ outp) {
  constexpr int K = 1024;
  constexpr int NT = BN / 64;  // 32x32 n-tiles per wave
  __shared__ __align__(16) half_t a_lds[128 * 64];
  __shared__ __align__(16) half_t b_lds[BN * 64];
  const int t = threadIdx.x;
  const int wave = t >> 6, lane = t & 63;
  const int l31 = lane & 31, hw = lane >> 5;
  const int wm = wave >> 1, wn = wave & 1;
  const int row0 = blockIdx.y * 128, col0 = blockIdx.x * BN;

  floatx16 acc[2][NT];
#pragma unroll
  for (int i = 0; i < 2; ++i)
#pragma unroll
    for (int j = 0; j < NT; ++j)
#pragma unroll
      for (int r = 0; r < 16; ++r) acc[i][j][r] = 0.f;

  for (int k0 = 0; k0 < K; k0 += 64) {
    // A: 128 rows x 8 chunks(16B) = 1024 segs, 4/thread
#pragma unroll
    for (int hi = 0; hi < 4; ++hi) {
      int s = t + hi * 256;
      int row = s >> 3, c = s & 7;
      int sc = c ^ (row & 7);
      gl2lds16(A + (size_t)(row0 + row) * K + (k0 + sc * 8), a_lds + (wave * 64 + hi * 256) * 8);
    }
    // B: BN rows x 8 chunks
#pragma unroll
    for (int hi = 0; hi < BN / 32; ++hi) {
      int s = t + hi * 256;
      int row = s >> 3, c = s & 7;
      int sc = c ^ (row & 7);
      gl2lds16(Bt + (size_t)(col0 + row) * K + (k0 + sc * 8), b_lds + (wave * 64 + hi * 256) * 8);
    }
    __syncthreads();
    half8 af[2][4], bf[NT][4];
#pragma unroll
    for (int mt = 0; mt < 2; ++mt) {
      int row = wm * 64 + mt * 32 + l31;
#pragma unroll
      for (int kf = 0; kf < 4; ++kf)
        af[mt][kf] = *(const half8*)(a_lds + row * 64 + ((kf * 2 + hw) ^ (row & 7)) * 8);
    }
#pragma unroll
    for (int nt = 0; nt < NT; ++nt) {
      int row = wn * (BN / 2) + nt * 32 + l31;
#pragma unroll
      for (int kf = 0; kf < 4; ++kf)
        bf[nt][kf] = *(const half8*)(b_lds + row * 64 + ((kf * 2 + hw) ^ (row & 7)) * 8);
    }
#pragma unroll
    for (int kf = 0; kf < 4; ++kf)
#pragma unroll
      for (int mt = 0; mt < 2; ++mt)
#pragma unroll
        for (int nt = 0; nt < NT; ++nt)
          acc[mt][nt] =
              __builtin_amdgcn_mfma_f32_32x32x16_f16(af[mt][kf], bf[nt][kf], acc[mt][nt], 0, 0, 0);
    __syncthreads();
  }

  // C/D 32x32 mapping: col = lane&31, row = (r&3) + 8*(r>>2) + 4*(lane>>5)
  if (MODE == 0) {
    const int which = col0 >> 10;
#pragma unroll
    for (int mt = 0; mt < 2; ++mt)
#pragma unroll
      for (int nt = 0; nt < NT; ++nt) {
        int growb = row0 + wm * 64 + mt * 32;
        int gcol = col0 + wn * (BN / 2) + nt * 32 + l31;
        int hc = gcol & 1023, h = hc >> 6, d = hc & 63;
        if (which == 2) {
#pragma unroll
          for (int rq = 0; rq < 4; ++rq) {
            int grow = growb + 8 * rq + 4 * hw;
            int b = grow >> 11, n0 = grow & 2047;
            int bh = b * NH + h;
            half4_t h4;
            h4.x = (half_t)acc[mt][nt][rq * 4 + 0];
            h4.y = (half_t)acc[mt][nt][rq * 4 + 1];
            h4.z = (half_t)acc[mt][nt][rq * 4 + 2];
            h4.w = (half_t)acc[mt][nt][rq * 4 + 3];
            *(half4_t*)(vT16 + ((size_t)bh * DH + d) * SEQ + n0) = h4;
          }
        } else {
#pragma unroll
          for (int r = 0; r < 16; ++r) {
            int grow = growb + (r & 3) + 8 * (r >> 2) + 4 * hw;
            int b = grow >> 11, n = grow & 2047;
            int bh = b * NH + h;
            float v = acc[mt][nt][r];
            if (which == 0)
              q16[((size_t)bh * SEQ + n) * DH + d] =
                  (half_t)(v * 0.1803368801111204f);  // fold SCALE * log2(e)
            else
              k16[((size_t)bh * SEQ + n) * DH + d] = (half_t)v;
          }
        }
      }
  } else {
#pragma unroll
    for (int mt = 0; mt < 2; ++mt)
#pragma unroll
      for (int nt = 0; nt < NT; ++nt) {
        int growb = row0 + wm * 64 + mt * 32;
        int gcol = col0 + wn * (BN / 2) + nt * 32 + l31;
#pragma unroll
        for (int r = 0; r < 16; ++r) {
          int grow = growb + (r & 3) + 8 * (r >> 2) + 4 * hw;
          outp[(size_t)grow * DIM_ + gcol] = acc[mt][nt][r];
        }
      }
  }
}

// Flash attention pass 1, all-32x32x16 (full-rate shape).
// Block = 4 waves x 32 q = 128 q-rows; j-slice SEQ/NJS, tiles of 64.
// S^T = mfma(K,Q): C col = l31 = q -> lane-local P row; PV A-frag row = l31 = q
// matches directly. The PV K-slices use a sigma-permuted j-order
// (k=8*hw+i <-> j = 16s + {0-3,8-11}+4hw) so the A-frag is a lane-uniform
// cvt_pkrtz pack of the lane's own exp outputs (zero shuffles); V B-frags are
// read in the same sigma order as two half4 ds_reads. psum = VALU adds +
// one shfl_xor(32) at the end. launch_bounds(256,3): cap regs for 3 waves/SIMD.
__global__ __launch_bounds__(256, 3) void attn_p1(const half_t* __restrict__ q16,
                                                  const half_t* __restrict__ k16,
                                                  const half_t* __restrict__ vT16,
                                                  half_t* __restrict__ opart,
                                                  float* __restrict__ psums) {
  __shared__ __align__(16) half_t k_lds[2][64 * 64];  // [j][d]
  __shared__ __align__(16) half_t v_lds[2][64 * 64];  // vT: [d][j]

  const int t = threadIdx.x;
  const int wave = t >> 6, lane = t & 63;
  const int l31 = lane & 31, hw = lane >> 5;
  const int blk = blockIdx.x;
  const int js = blk & (NJS - 1), qt = (blk >> 1) & 15, bh = blk >> 5;
  const half_t* qp = q16 + (size_t)bh * SEQ * DH;
  const half_t* kp = k16 + (size_t)bh * SEQ * DH;
  const half_t* vp = vT16 + (size_t)bh * DH * SEQ;
  const int q0w = qt * 128 + wave * 32;
  const int jbase = js * (SEQ / NJS);
  constexpr int NJT = (SEQ / NJS) / 64;  // 16

  // staging offsets: 512 segs of 16B (64 rows x 8 chunks), chunk XOR row&7
  const int s0 = t, s1 = t + 256;
  const int r0_ = s0 >> 3, c0_ = (s0 & 7) ^ (r0_ & 7);
  const int r1_ = s1 >> 3, c1_ = (s1 & 7) ^ (r1_ & 7);

  // Q fragments, B-operand 32x32x16: col = l31 = q, k = kf*16 + hw*8 + i
  half8 qf[4];
#pragma unroll
  for (int kf = 0; kf < 4; ++kf)
    qf[kf] = *(const half8*)(qp + (size_t)(q0w + l31) * DH + kf * 16 + hw * 8);

  floatx16 o[2];  // [d-tile]; C/D: col=l31=d, row=(r&3)+8(r>>2)+4hw = q
#pragma unroll
  for (int i = 0; i < 2; ++i)
#pragma unroll
    for (int r = 0; r < 16; ++r) o[i][r] = 0.f;
  float psum = 0.f;

  // prologue: stage tile jbase into buffer 0
  gl2lds16(kp + (size_t)(jbase + r0_) * DH + c0_ * 8, &k_lds[0][(wave * 64) * 8]);
  gl2lds16(vp + (size_t)r0_ * SEQ + jbase + c0_ * 8, &v_lds[0][(wave * 64) * 8]);
  gl2lds16(kp + (size_t)(jbase + r1_) * DH + c1_ * 8, &k_lds[0][(wave * 64 + 256) * 8]);
  gl2lds16(vp + (size_t)r1_ * SEQ + jbase + c1_ * 8, &v_lds[0][(wave * 64 + 256) * 8]);

  int cur = 0;
  for (int jt = 0; jt < NJT; ++jt) {
    __syncthreads();  // publishes buf[cur], protects buf[cur^1]

    if (jt + 1 < NJT) {
      const int j0 = jbase + (jt + 1) * 64, nb = cur ^ 1;
      gl2lds16(kp + (size_t)(j0 + r0_) * DH + c0_ * 8, &k_lds[nb][(wave * 64) * 8]);
      gl2lds16(vp + (size_t)r0_ * SEQ + j0 + c0_ * 8, &v_lds[nb][(wave * 64) * 8]);
      gl2lds16(kp + (size_t)(j0 + r1_) * DH + c1_ * 8, &k_lds[nb][(wave * 64 + 256) * 8]);
      gl2lds16(vp + (size_t)r1_ * SEQ + j0 + c1_ * 8, &v_lds[nb][(wave * 64 + 256) * 8]);
    }

    const half_t* kl = k_lds[cur];
    const half_t* vl = v_lds[cur];

    // S^T[j 64][q 32]: A = K (m=j, 2 tiles), B = Q. 8 MFMAs of 32x32x16.
    floatx16 st[2];
#pragma unroll
    for (int m = 0; m < 2; ++m)
#pragma unroll
      for (int r = 0; r < 16; ++r) st[m][r] = 0.f;
    __builtin_amdgcn_s_setprio(1);
#pragma unroll
    for (int kf = 0; kf < 4; ++kf)
#pragma unroll
      for (int m = 0; m < 2; ++m) {
        int row = m * 32 + l31;  // j
        half8 kb = *(const half8*)(kl + row * 64 + ((kf * 2 + hw) ^ (row & 7)) * 8);
        st[m] = __builtin_amdgcn_mfma_f32_32x32x16_f16(kb, qf[kf], st[m], 0, 0, 0);
      }
    __builtin_amdgcn_s_setprio(0);

    // exp2 -> psum + P A-frags (lane-uniform pack; sigma j-order)
    half8 pa[2][2];  // [m][lo/hi]
#pragma unroll
    for (int m = 0; m < 2; ++m) {
      float p[16];
#pragma unroll
      for (int r = 0; r < 16; ++r) p[r] = fexp2(st[m][r]);
      float a0 = (p[0] + p[1]) + (p[2] + p[3]);
      float a1 = (p[4] + p[5]) + (p[6] + p[7]);
      float a2 = (p[8] + p[9]) + (p[10] + p[11]);
      float a3 = (p[12] + p[13]) + (p[14] + p[15]);
      psum += (a0 + a1) + (a2 + a3);
      pa[m][0] = pack8(p[0], p[1], p[2], p[3], p[4], p[5], p[6], p[7]);
      pa[m][1] = pack8(p[8], p[9], p[10], p[11], p[12], p[13], p[14], p[15]);
    }

    // O[q 32][d 64] += P@V. 8 MFMAs of 32x32x16; B-frags in sigma j-order:
    // k=8hw+i <-> j = 16s + (i&3) + 8*(i>>2) + 4*hw
    __builtin_amdgcn_s_setprio(1);
#pragma unroll
    for (int s = 0; s < 4; ++s) {
#pragma unroll
      for (int dt = 0; dt < 2; ++dt) {
        int row = dt * 32 + l31;  // d
        int ca = ((s * 2 + 0) ^ (row & 7));
        int cb = ((s * 2 + 1) ^ (row & 7));
        half4_t va = *(const half4_t*)(vl + row * 64 + ca * 8 + hw * 4);
        half4_t vb = *(const half4_t*)(vl + row * 64 + cb * 8 + hw * 4);
        half8 v8 = __builtin_shufflevector(va, vb, 0, 1, 2, 3, 4, 5, 6, 7);
        o[dt] = __builtin_amdgcn_mfma_f32_32x32x16_f16(pa[s >> 1][s & 1], v8, o[dt], 0, 0, 0);
      }
    }
    __builtin_amdgcn_s_setprio(0);
    cur ^= 1;
  }

  // psum: lane holds sum over its hw-half's j for q = q0w + l31
  psum += __shfl_xor(psum, 32, 64);
  if (hw == 0) psums[((size_t)(js * 32 + bh)) * SEQ + q0w + l31] = psum;

  // unnormalized O -> fp16 partials; q = q0w + (r&3)+8(r>>2)+4hw, d = dt*32+l31
#pragma unroll
  for (int dt = 0; dt < 2; ++dt)
#pragma unroll
    for (int r = 0; r < 16; ++r) {
      int n = q0w + (r & 3) + 8 * (r >> 2) + 4 * hw;
      opart[((size_t)(js * 32 + bh) * SEQ + n) * DH + dt * 32 + l31] = (half_t)o[dt][r];
    }
}

// combine: out = (sum_js O_js) * softmax(head_w)[h] / (sum_js ps_js), fp16 attn16
__global__ __launch_bounds__(256) void combine(const half_t* __restrict__ opart,
                                               const float* __restrict__ psums,
                                               const float* __restrict__ head_w,
                                               half_t* __restrict__ attn16) {
  int idx = blockIdx.x * blockDim.x + threadIdx.x;  // 1M threads, 4 d each
  int d4 = idx & 15, n = (idx >> 4) & 2047, bh = idx >> 15;
  int h = bh & 15, b = bh >> 4;
  const size_t jstr = (size_t)32 * SEQ * DH;
  size_t off = ((size_t)bh * SEQ + n) * DH + d4 * 4;

  float sx = 0.f, sy = 0.f, sz = 0.f, sw2 = 0.f, ps = 0.f;
#pragma unroll
  for (int js = 0; js < NJS; ++js) {
    half4_t ov = *(const half4_t*)(opart + js * jstr + off);
    sx += (float)ov.x; sy += (float)ov.y; sz += (float)ov.z; sw2 += (float)ov.w;
    ps += psums[(size_t)js * 32 * SEQ + (size_t)bh * SEQ + n];
  }

  float mw = head_w[0];
#pragma unroll
  for (int i = 1; i < NH; ++i) mw = fmaxf(mw, head_w[i]);
  float sw = 0.f;
#pragma unroll
  for (int i = 0; i < NH; ++i) sw += __expf(head_w[i] - mw);
  float hwv = __expf(head_w[h] - mw) / sw;

  float scl = hwv / ps;
  half4_t r;
  r.x = (half_t)(sx * scl);
  r.y = (half_t)(sy * scl);
  r.z = (half_t)(sz * scl);
  r.w = (half_t)(sw2 * scl);
  *(half4_t*)(attn16 + ((size_t)(b * SEQ + n)) * DIM_ + h * DH + d4 * 4) = r;
}

extern "C" void kernel_launch(void* const* d_in, const int* in_sizes, int n_in,
                              void* d_out, int out_size, void* d_ws, size_t ws_size,
                              hipStream_t stream) {
  const float* x = (const float*)d_in[0];
  const float* w_qkv = (const float*)d_in[1];
  const float* w_proj = (const float*)d_in[2];
  const float* head_w = (const float*)d_in[3];
  float* out = (float*)d_out;

  half_t* x16 = (half_t*)d_ws;                          // 4096*1024
  half_t* wq16 = x16 + (size_t)ROWS * DIM_;             // 3072*1024
  half_t* wp16 = wq16 + (size_t)3 * DIM_ * DIM_;        // 1024*1024
  half_t* q16 = wp16 + (size_t)DIM_ * DIM_;             // [B,H,N,Dh] (scaled by 0.125*log2e)
  half_t* k16 = q16 + (size_t)ROWS * DIM_;              // [B,H,N,Dh]
  half_t* vT16 = k16 + (size_t)ROWS * DIM_;             // [B,H,Dh,N]
  half_t* attn16 = vT16 + (size_t)ROWS * DIM_;          // [B*N, DIM]
  half_t* opart = attn16 + (size_t)ROWS * DIM_;         // [NJS][32][2048][64] fp16
  float* psums = (float*)(opart + (size_t)NJS * 32 * SEQ * DH);  // [NJS][32][2048] f32

  const int nx = ROWS * DIM_ / 4, nq = 3 * DIM_ * DIM_ / 4, np = DIM_ * DIM_ / 4;
  convert_all<<<(nx + nq + np) / 256, 256, 0, stream>>>((const float4*)x, (const float4*)w_qkv,
                                                        (const float4*)w_proj, (half4_t*)x16,
                                                        nx, nq, np);

  gemm32<0, 128><<<dim3(24, 32), 256, 0, stream>>>(x16, wq16, q16, k16, vT16, nullptr);
  attn_p1<<<32 * 16 * NJS, 256, 0, stream>>>(q16, k16, vT16, opart, psums);
  combine<<<(32 * SEQ * DH / 4) / 256, 256, 0, stream>>>(opart, psums, head_w, attn16);
  gemm32<1, 64><<<dim3(16, 32), 256, 0, stream>>>(attn16, wp16, nullptr, nullptr, nullptr, out);
}

// Round 5
// 186.063 us; speedup vs baseline: 1.0732x; 1.0182x over previous
//
#include <hip/hip_runtime.h>

typedef _Float16 half_t;
typedef _Float16 half8 __attribute__((ext_vector_type(8)));
typedef _Float16 half4_t __attribute__((ext_vector_type(4)));
typedef _Float16 half2_t __attribute__((ext_vector_type(2)));
typedef float floatx4 __attribute__((ext_vector_type(4)));
typedef float floatx16 __attribute__((ext_vector_type(16)));
typedef unsigned int uint4v __attribute__((ext_vector_type(4)));
typedef unsigned int uint2v __attribute__((ext_vector_type(2)));

#define B_SZ 2
#define SEQ 2048
#define DIM_ 1024
#define NH 16
#define DH 64
#define ROWS (B_SZ * SEQ)   // 4096
#define NJS 4               // j-split ways; grid 32*16*NJS = 2048 blocks

// async global->LDS, 16B per lane; LDS dest = wave-uniform base + lane*16
__device__ __forceinline__ void gl2lds16(const void* g, void* l) {
  __builtin_amdgcn_global_load_lds((const __attribute__((address_space(1))) unsigned int*)g,
                                   (__attribute__((address_space(3))) unsigned int*)l, 16, 0, 0);
}

// exp2 (single v_exp_f32; log2(e) folded into q scale at GEMM epilogue)
__device__ __forceinline__ float fexp2(float x) {
#if __has_builtin(__builtin_amdgcn_exp2f)
  return __builtin_amdgcn_exp2f(x);
#else
  return __expf(x * 0.6931471805599453f);
#endif
}

__device__ __forceinline__ unsigned cvtpk_u32(float a, float b) {
#if __has_builtin(__builtin_amdgcn_cvt_pkrtz)
  return __builtin_bit_cast(unsigned, __builtin_amdgcn_cvt_pkrtz(a, b));
#else
  half2_t h; h.x = (half_t)a; h.y = (half_t)b;
  return __builtin_bit_cast(unsigned, h);
#endif
}

// one kernel converts x, w_qkv, w_proj (contiguous in ws) fp32->fp16
__global__ __launch_bounds__(256) void convert_all(const float4* __restrict__ x,
                                                   const float4* __restrict__ wq,
                                                   const float4* __restrict__ wp,
                                                   half4_t* __restrict__ dst,
                                                   int nx, int nq, int np) {
  int i = blockIdx.x * blockDim.x + threadIdx.x;
  float4 v;
  if (i < nx) v = x[i];
  else if (i < nx + nq) v = wq[i - nx];
  else if (i < nx + nq + np) v = wp[i - nx - nq];
  else return;
  half4_t h;
  h.x = (half_t)v.x; h.y = (half_t)v.y; h.z = (half_t)v.z; h.w = (half_t)v.w;
  dst[i] = h;
}

// C = A[4096][1024] @ Bt[N][1024]^T. 32x32x16 MFMA, BK=64, 128xBN tile, 4 waves.
// MODE 0 (BN=128): qkv epilogue. MODE 1 (BN=64): proj fp32 out.
template <int MODE, int BN>
__global__ __launch_bounds__(256) void gemm32(const half_t* __restrict__ A,
                                              const half_t* __restrict__ Bt,
                                              half_t* __restrict__ q16,
                                              half_t* __restrict__ k16,
                                              half_t* __restrict__ vT16,
                                              float* __restrict__ outp) {
  constexpr int K = 1024;
  constexpr int NT = BN / 64;  // 32x32 n-tiles per wave
  __shared__ __align__(16) half_t a_lds[128 * 64];
  __shared__ __align__(16) half_t b_lds[BN * 64];
  const int t = threadIdx.x;
  const int wave = t >> 6, lane = t & 63;
  const int l31 = lane & 31, hw = lane >> 5;
  const int wm = wave >> 1, wn = wave & 1;
  const int row0 = blockIdx.y * 128, col0 = blockIdx.x * BN;

  floatx16 acc[2][NT];
#pragma unroll
  for (int i = 0; i < 2; ++i)
#pragma unroll
    for (int j = 0; j < NT; ++j)
#pragma unroll
      for (int r = 0; r < 16; ++r) acc[i][j][r] = 0.f;

  for (int k0 = 0; k0 < K; k0 += 64) {
    // A: 128 rows x 8 chunks(16B) = 1024 segs, 4/thread
#pragma unroll
    for (int hi = 0; hi < 4; ++hi) {
      int s = t + hi * 256;
      int row = s >> 3, c = s & 7;
      int sc = c ^ (row & 7);
      gl2lds16(A + (size_t)(row0 + row) * K + (k0 + sc * 8), a_lds + (wave * 64 + hi * 256) * 8);
    }
    // B: BN rows x 8 chunks
#pragma unroll
    for (int hi = 0; hi < BN / 32; ++hi) {
      int s = t + hi * 256;
      int row = s >> 3, c = s & 7;
      int sc = c ^ (row & 7);
      gl2lds16(Bt + (size_t)(col0 + row) * K + (k0 + sc * 8), b_lds + (wave * 64 + hi * 256) * 8);
    }
    __syncthreads();
    half8 af[2][4], bf[NT][4];
#pragma unroll
    for (int mt = 0; mt < 2; ++mt) {
      int row = wm * 64 + mt * 32 + l31;
#pragma unroll
      for (int kf = 0; kf < 4; ++kf)
        af[mt][kf] = *(const half8*)(a_lds + row * 64 + ((kf * 2 + hw) ^ (row & 7)) * 8);
    }
#pragma unroll
    for (int nt = 0; nt < NT; ++nt) {
      int row = wn * (BN / 2) + nt * 32 + l31;
#pragma unroll
      for (int kf = 0; kf < 4; ++kf)
        bf[nt][kf] = *(const half8*)(b_lds + row * 64 + ((kf * 2 + hw) ^ (row & 7)) * 8);
    }
#pragma unroll
    for (int kf = 0; kf < 4; ++kf)
#pragma unroll
      for (int mt = 0; mt < 2; ++mt)
#pragma unroll
        for (int nt = 0; nt < NT; ++nt)
          acc[mt][nt] =
              __builtin_amdgcn_mfma_f32_32x32x16_f16(af[mt][kf], bf[nt][kf], acc[mt][nt], 0, 0, 0);
    __syncthreads();
  }

  // C/D 32x32 mapping: col = lane&31, row = (r&3) + 8*(r>>2) + 4*(lane>>5)
  if (MODE == 0) {
    const int which = col0 >> 10;
#pragma unroll
    for (int mt = 0; mt < 2; ++mt)
#pragma unroll
      for (int nt = 0; nt < NT; ++nt) {
        int growb = row0 + wm * 64 + mt * 32;
        int gcol = col0 + wn * (BN / 2) + nt * 32 + l31;
        int hc = gcol & 1023, h = hc >> 6, d = hc & 63;
        if (which == 2) {
#pragma unroll
          for (int rq = 0; rq < 4; ++rq) {
            int grow = growb + 8 * rq + 4 * hw;
            int b = grow >> 11, n0 = grow & 2047;
            int bh = b * NH + h;
            half4_t h4;
            h4.x = (half_t)acc[mt][nt][rq * 4 + 0];
            h4.y = (half_t)acc[mt][nt][rq * 4 + 1];
            h4.z = (half_t)acc[mt][nt][rq * 4 + 2];
            h4.w = (half_t)acc[mt][nt][rq * 4 + 3];
            *(half4_t*)(vT16 + ((size_t)bh * DH + d) * SEQ + n0) = h4;
          }
        } else {
#pragma unroll
          for (int r = 0; r < 16; ++r) {
            int grow = growb + (r & 3) + 8 * (r >> 2) + 4 * hw;
            int b = grow >> 11, n = grow & 2047;
            int bh = b * NH + h;
            float v = acc[mt][nt][r];
            if (which == 0)
              q16[((size_t)bh * SEQ + n) * DH + d] =
                  (half_t)(v * 0.1803368801111204f);  // fold SCALE * log2(e)
            else
              k16[((size_t)bh * SEQ + n) * DH + d] = (half_t)v;
          }
        }
      }
  } else {
#pragma unroll
    for (int mt = 0; mt < 2; ++mt)
#pragma unroll
      for (int nt = 0; nt < NT; ++nt) {
        int growb = row0 + wm * 64 + mt * 32;
        int gcol = col0 + wn * (BN / 2) + nt * 32 + l31;
#pragma unroll
        for (int r = 0; r < 16; ++r) {
          int grow = growb + (r & 3) + 8 * (r >> 2) + 4 * hw;
          outp[(size_t)grow * DIM_ + gcol] = acc[mt][nt][r];
        }
      }
  }
}

// Flash attention pass 1, all-32x32x16. Block = 4 waves x 32 q = 128 q-rows;
// j-slice SEQ/NJS (NJS=4 -> 2048 blocks -> LDS-capped 5 blocks/CU residency).
// S^T = mfma(K,Q): lane l31 = q. PV A-frags built in NATURAL k-order via
// v_cvt_pkrtz + v_permlane32_swap (cross-half j values live in the partner
// lane); V B-frags are then natural b128 reads (same swizzled access shape as
// the K reads) -- removes the 8B sigma reads that caused 4-way bank aliasing.
__global__ __launch_bounds__(256, 3) void attn_p1(const half_t* __restrict__ q16,
                                                  const half_t* __restrict__ k16,
                                                  const half_t* __restrict__ vT16,
                                                  half_t* __restrict__ opart,
                                                  float* __restrict__ psums) {
  __shared__ __align__(16) half_t k_lds[2][64 * 64];  // [j][d]
  __shared__ __align__(16) half_t v_lds[2][64 * 64];  // vT: [d][j]

  const int t = threadIdx.x;
  const int wave = t >> 6, lane = t & 63;
  const int l31 = lane & 31, hw = lane >> 5;
  const int blk = blockIdx.x;
  const int js = blk & (NJS - 1), qt = (blk / NJS) & 15, bh = blk / (NJS * 16);
  const half_t* qp = q16 + (size_t)bh * SEQ * DH;
  const half_t* kp = k16 + (size_t)bh * SEQ * DH;
  const half_t* vp = vT16 + (size_t)bh * DH * SEQ;
  const int q0w = qt * 128 + wave * 32;
  const int jbase = js * (SEQ / NJS);
  constexpr int NJT = (SEQ / NJS) / 64;  // 8

  // staging offsets: 512 segs of 16B (64 rows x 8 chunks), chunk XOR row&7
  const int s0 = t, s1 = t + 256;
  const int r0_ = s0 >> 3, c0_ = (s0 & 7) ^ (r0_ & 7);
  const int r1_ = s1 >> 3, c1_ = (s1 & 7) ^ (r1_ & 7);

  // Q fragments, B-operand 32x32x16: col = l31 = q, k = kf*16 + hw*8 + i
  half8 qf[4];
#pragma unroll
  for (int kf = 0; kf < 4; ++kf)
    qf[kf] = *(const half8*)(qp + (size_t)(q0w + l31) * DH + kf * 16 + hw * 8);

  floatx16 o[2];  // [d-tile]; C/D: col=l31=d, row=(r&3)+8(r>>2)+4hw = q
#pragma unroll
  for (int i = 0; i < 2; ++i)
#pragma unroll
    for (int r = 0; r < 16; ++r) o[i][r] = 0.f;
  float psum = 0.f;

  // prologue: stage tile jbase into buffer 0
  gl2lds16(kp + (size_t)(jbase + r0_) * DH + c0_ * 8, &k_lds[0][(wave * 64) * 8]);
  gl2lds16(vp + (size_t)r0_ * SEQ + jbase + c0_ * 8, &v_lds[0][(wave * 64) * 8]);
  gl2lds16(kp + (size_t)(jbase + r1_) * DH + c1_ * 8, &k_lds[0][(wave * 64 + 256) * 8]);
  gl2lds16(vp + (size_t)r1_ * SEQ + jbase + c1_ * 8, &v_lds[0][(wave * 64 + 256) * 8]);

  int cur = 0;
  for (int jt = 0; jt < NJT; ++jt) {
    __syncthreads();  // publishes buf[cur], protects buf[cur^1]

    if (jt + 1 < NJT) {
      const int j0 = jbase + (jt + 1) * 64, nb = cur ^ 1;
      gl2lds16(kp + (size_t)(j0 + r0_) * DH + c0_ * 8, &k_lds[nb][(wave * 64) * 8]);
      gl2lds16(vp + (size_t)r0_ * SEQ + j0 + c0_ * 8, &v_lds[nb][(wave * 64) * 8]);
      gl2lds16(kp + (size_t)(j0 + r1_) * DH + c1_ * 8, &k_lds[nb][(wave * 64 + 256) * 8]);
      gl2lds16(vp + (size_t)r1_ * SEQ + j0 + c1_ * 8, &v_lds[nb][(wave * 64 + 256) * 8]);
    }

    const half_t* kl = k_lds[cur];
    const half_t* vl = v_lds[cur];

    // S^T[j 64][q 32]: A = K (m=j, 2 tiles), B = Q. 8 MFMAs of 32x32x16.
    floatx16 st[2];
#pragma unroll
    for (int m = 0; m < 2; ++m)
#pragma unroll
      for (int r = 0; r < 16; ++r) st[m][r] = 0.f;
    __builtin_amdgcn_s_setprio(1);
#pragma unroll
    for (int kf = 0; kf < 4; ++kf)
#pragma unroll
      for (int m = 0; m < 2; ++m) {
        int row = m * 32 + l31;  // j
        half8 kb = *(const half8*)(kl + row * 64 + ((kf * 2 + hw) ^ (row & 7)) * 8);
        st[m] = __builtin_amdgcn_mfma_f32_32x32x16_f16(kb, qf[kf], st[m], 0, 0, 0);
      }
    __builtin_amdgcn_s_setprio(0);

    // exp2 -> psum + natural-k PV A-frags.
    // C-layout row-in-tile for reg r at lane-half hwL: (r&3) + 8*(r>>2) + 4*hwL.
    // k-slice ks covers j = ks*16 + 0..15; lane half hw supplies k = hw*8+i.
    // words: w0=(k0,k1) w1=(k2,k3) w2=(k4,k5) w3=(k6,k7) (k offsets per half):
    //   hw=0 lane: w0,w1 = own (r&3 pair at rb), w2,w3 = partner's same regs
    //   hw=1 lane: w0,w1 = partner's (rb+4..7), w2,w3 = own (rb+4..7)
    // permlane32_swap(uA,uC): .x = w0 for both halves, .y = w2 for both.
    half8 pa[4];
#pragma unroll
    for (int ks = 0; ks < 4; ++ks) {
      const int m = ks >> 1, rb = (ks & 1) * 8;
      float p0 = fexp2(st[m][rb + 0]);
      float p1 = fexp2(st[m][rb + 1]);
      float p2 = fexp2(st[m][rb + 2]);
      float p3 = fexp2(st[m][rb + 3]);
      float p4 = fexp2(st[m][rb + 4]);
      float p5 = fexp2(st[m][rb + 5]);
      float p6 = fexp2(st[m][rb + 6]);
      float p7 = fexp2(st[m][rb + 7]);
      psum += ((p0 + p1) + (p2 + p3)) + ((p4 + p5) + (p6 + p7));
      unsigned uA = cvtpk_u32(p0, p1);
      unsigned uB = cvtpk_u32(p2, p3);
      unsigned uC = cvtpk_u32(p4, p5);
      unsigned uD = cvtpk_u32(p6, p7);
#if __has_builtin(__builtin_amdgcn_permlane32_swap)
      uint2v sAC = __builtin_bit_cast(uint2v, __builtin_amdgcn_permlane32_swap(uA, uC, false, false));
      uint2v sBD = __builtin_bit_cast(uint2v, __builtin_amdgcn_permlane32_swap(uB, uD, false, false));
      uint4v u;
      u.x = sAC.x; u.y = sBD.x; u.z = sAC.y; u.w = sBD.y;
#else
      unsigned xA = (unsigned)__shfl_xor((int)uA, 32, 64);
      unsigned xB = (unsigned)__shfl_xor((int)uB, 32, 64);
      unsigned xC = (unsigned)__shfl_xor((int)uC, 32, 64);
      unsigned xD = (unsigned)__shfl_xor((int)uD, 32, 64);
      uint4v u;
      u.x = hw ? xC : uA;
      u.y = hw ? xD : uB;
      u.z = hw ? uC : xA;
      u.w = hw ? uD : xB;
#endif
      pa[ks] = __builtin_bit_cast(half8, u);
    }

    // O[q 32][d 64] += P@V. 8 MFMAs; V B-frag natural b128:
    // lane l31 = d-col (vT row), k = j = ks*16 + hw*8 + i -> chunk ks*2+hw.
    __builtin_amdgcn_s_setprio(1);
#pragma unroll
    for (int ks = 0; ks < 4; ++ks)
#pragma unroll
      for (int dt = 0; dt < 2; ++dt) {
        int row = dt * 32 + l31;  // d
        half8 vb = *(const half8*)(vl + row * 64 + ((ks * 2 + hw) ^ (row & 7)) * 8);
        o[dt] = __builtin_amdgcn_mfma_f32_32x32x16_f16(pa[ks], vb, o[dt], 0, 0, 0);
      }
    __builtin_amdgcn_s_setprio(0);
    cur ^= 1;
  }

  // psum: lane holds sum over its half's j for q = q0w + l31
  psum += __shfl_xor(psum, 32, 64);
  if (hw == 0) psums[((size_t)(js * 32 + bh)) * SEQ + q0w + l31] = psum;

  // unnormalized O -> fp16 partials; q = q0w + (r&3)+8(r>>2)+4hw, d = dt*32+l31
#pragma unroll
  for (int dt = 0; dt < 2; ++dt)
#pragma unroll
    for (int r = 0; r < 16; ++r) {
      int n = q0w + (r & 3) + 8 * (r >> 2) + 4 * hw;
      opart[((size_t)(js * 32 + bh) * SEQ + n) * DH + dt * 32 + l31] = (half_t)o[dt][r];
    }
}

// combine: out = (sum_js O_js) * softmax(head_w)[h] / (sum_js ps_js), fp16 attn16
__global__ __launch_bounds__(256) void combine(const half_t* __restrict__ opart,
                                               const float* __restrict__ psums,
                                               const float* __restrict__ head_w,
                                               half_t* __restrict__ attn16) {
  int idx = blockIdx.x * blockDim.x + threadIdx.x;  // 1M threads, 4 d each
  int d4 = idx & 15, n = (idx >> 4) & 2047, bh = idx >> 15;
  int h = bh & 15, b = bh >> 4;
  const size_t jstr = (size_t)32 * SEQ * DH;
  size_t off = ((size_t)bh * SEQ + n) * DH + d4 * 4;

  float sx = 0.f, sy = 0.f, sz = 0.f, sw2 = 0.f, ps = 0.f;
#pragma unroll
  for (int js = 0; js < NJS; ++js) {
    half4_t ov = *(const half4_t*)(opart + js * jstr + off);
    sx += (float)ov.x; sy += (float)ov.y; sz += (float)ov.z; sw2 += (float)ov.w;
    ps += psums[(size_t)js * 32 * SEQ + (size_t)bh * SEQ + n];
  }

  float mw = head_w[0];
#pragma unroll
  for (int i = 1; i < NH; ++i) mw = fmaxf(mw, head_w[i]);
  float sw = 0.f;
#pragma unroll
  for (int i = 0; i < NH; ++i) sw += __expf(head_w[i] - mw);
  float hwv = __expf(head_w[h] - mw) / sw;

  float scl = hwv / ps;
  half4_t r;
  r.x = (half_t)(sx * scl);
  r.y = (half_t)(sy * scl);
  r.z = (half_t)(sz * scl);
  r.w = (half_t)(sw2 * scl);
  *(half4_t*)(attn16 + ((size_t)(b * SEQ + n)) * DIM_ + h * DH + d4 * 4) = r;
}

extern "C" void kernel_launch(void* const* d_in, const int* in_sizes, int n_in,
                              void* d_out, int out_size, void* d_ws, size_t ws_size,
                              hipStream_t stream) {
  const float* x = (const float*)d_in[0];
  const float* w_qkv = (const float*)d_in[1];
  const float* w_proj = (const float*)d_in[2];
  const float* head_w = (const float*)d_in[3];
  float* out = (float*)d_out;

  half_t* x16 = (half_t*)d_ws;                          // 4096*1024
  half_t* wq16 = x16 + (size_t)ROWS * DIM_;             // 3072*1024
  half_t* wp16 = wq16 + (size_t)3 * DIM_ * DIM_;        // 1024*1024
  half_t* q16 = wp16 + (size_t)DIM_ * DIM_;             // [B,H,N,Dh] (scaled by 0.125*log2e)
  half_t* k16 = q16 + (size_t)ROWS * DIM_;              // [B,H,N,Dh]
  half_t* vT16 = k16 + (size_t)ROWS * DIM_;             // [B,H,Dh,N]
  half_t* attn16 = vT16 + (size_t)ROWS * DIM_;          // [B*N, DIM]
  half_t* opart = attn16 + (size_t)ROWS * DIM_;         // [NJS][32][2048][64] fp16
  float* psums = (float*)(opart + (size_t)NJS * 32 * SEQ * DH);  // [NJS][32][2048] f32
  // total: ~48MB fp16 bufs + 33.5MB opart + 1MB psums ~= 83MB workspace

  const int nx = ROWS * DIM_ / 4, nq = 3 * DIM_ * DIM_ / 4, np = DIM_ * DIM_ / 4;
  convert_all<<<(nx + nq + np) / 256, 256, 0, stream>>>((const float4*)x, (const float4*)w_qkv,
                                                        (const float4*)w_proj, (half4_t*)x16,
                                                        nx, nq, np);

  gemm32<0, 128><<<dim3(24, 32), 256, 0, stream>>>(x16, wq16, q16, k16, vT16, nullptr);
  attn_p1<<<32 * 16 * NJS, 256, 0, stream>>>(q16, k16, vT16, opart, psums);
  combine<<<(32 * SEQ * DH / 4) / 256, 256, 0, stream>>>(opart, psums, head_w, attn16);
  gemm32<1, 64><<<dim3(16, 32), 256, 0, stream>>>(attn16, wp16, nullptr, nullptr, nullptr, out);
}

// Round 6
// 181.437 us; speedup vs baseline: 1.1006x; 1.0255x over previous
//
#include <hip/hip_runtime.h>

typedef _Float16 half_t;
typedef _Float16 half8 __attribute__((ext_vector_type(8)));
typedef _Float16 half4_t __attribute__((ext_vector_type(4)));
typedef _Float16 half2_t __attribute__((ext_vector_type(2)));
typedef float floatx4 __attribute__((ext_vector_type(4)));
typedef float floatx16 __attribute__((ext_vector_type(16)));
typedef unsigned int uint4v __attribute__((ext_vector_type(4)));
typedef unsigned int uint2v __attribute__((ext_vector_type(2)));

#define B_SZ 2
#define SEQ 2048
#define DIM_ 1024
#define NH 16
#define DH 64
#define ROWS (B_SZ * SEQ)   // 4096
#define NJS 2               // j-split ways; grid 32*16*NJS = 1024 blocks = 4/CU

// async global->LDS, 16B per lane; LDS dest = wave-uniform base + lane*16
__device__ __forceinline__ void gl2lds16(const void* g, void* l) {
  __builtin_amdgcn_global_load_lds((const __attribute__((address_space(1))) unsigned int*)g,
                                   (__attribute__((address_space(3))) unsigned int*)l, 16, 0, 0);
}

// exp2 (single v_exp_f32; log2(e) folded into q scale at GEMM epilogue)
__device__ __forceinline__ float fexp2(float x) {
#if __has_builtin(__builtin_amdgcn_exp2f)
  return __builtin_amdgcn_exp2f(x);
#else
  return __expf(x * 0.6931471805599453f);
#endif
}

__device__ __forceinline__ unsigned cvtpk_u32(float a, float b) {
#if __has_builtin(__builtin_amdgcn_cvt_pkrtz)
  return __builtin_bit_cast(unsigned, __builtin_amdgcn_cvt_pkrtz(a, b));
#else
  half2_t h; h.x = (half_t)a; h.y = (half_t)b;
  return __builtin_bit_cast(unsigned, h);
#endif
}

// one kernel converts x, w_qkv, w_proj (contiguous in ws) fp32->fp16
__global__ __launch_bounds__(256) void convert_all(const float4* __restrict__ x,
                                                   const float4* __restrict__ wq,
                                                   const float4* __restrict__ wp,
                                                   half4_t* __restrict__ dst,
                                                   int nx, int nq, int np) {
  int i = blockIdx.x * blockDim.x + threadIdx.x;
  float4 v;
  if (i < nx) v = x[i];
  else if (i < nx + nq) v = wq[i - nx];
  else if (i < nx + nq + np) v = wp[i - nx - nq];
  else return;
  half4_t h;
  h.x = (half_t)v.x; h.y = (half_t)v.y; h.z = (half_t)v.z; h.w = (half_t)v.w;
  dst[i] = h;
}

// C = A[4096][1024] @ Bt[N][1024]^T. 32x32x16 MFMA, BK=64, 128xBN tile, 4 waves.
// MODE 0 (BN=128): qkv epilogue. MODE 1 (BN=64): proj fp32 out.
template <int MODE, int BN>
__global__ __launch_bounds__(256) void gemm32(const half_t* __restrict__ A,
                                              const half_t* __restrict__ Bt,
                                              half_t* __restrict__ q16,
                                              half_t* __restrict__ k16,
                                              half_t* __restrict__ vT16,
                                              float* __restrict__ outp) {
  constexpr int K = 1024;
  constexpr int NT = BN / 64;  // 32x32 n-tiles per wave
  __shared__ __align__(16) half_t a_lds[128 * 64];
  __shared__ __align__(16) half_t b_lds[BN * 64];
  const int t = threadIdx.x;
  const int wave = t >> 6, lane = t & 63;
  const int l31 = lane & 31, hw = lane >> 5;
  const int wm = wave >> 1, wn = wave & 1;
  const int row0 = blockIdx.y * 128, col0 = blockIdx.x * BN;

  floatx16 acc[2][NT];
#pragma unroll
  for (int i = 0; i < 2; ++i)
#pragma unroll
    for (int j = 0; j < NT; ++j)
#pragma unroll
      for (int r = 0; r < 16; ++r) acc[i][j][r] = 0.f;

  for (int k0 = 0; k0 < K; k0 += 64) {
    // A: 128 rows x 8 chunks(16B) = 1024 segs, 4/thread
#pragma unroll
    for (int hi = 0; hi < 4; ++hi) {
      int s = t + hi * 256;
      int row = s >> 3, c = s & 7;
      int sc = c ^ (row & 7);
      gl2lds16(A + (size_t)(row0 + row) * K + (k0 + sc * 8), a_lds + (wave * 64 + hi * 256) * 8);
    }
    // B: BN rows x 8 chunks
#pragma unroll
    for (int hi = 0; hi < BN / 32; ++hi) {
      int s = t + hi * 256;
      int row = s >> 3, c = s & 7;
      int sc = c ^ (row & 7);
      gl2lds16(Bt + (size_t)(col0 + row) * K + (k0 + sc * 8), b_lds + (wave * 64 + hi * 256) * 8);
    }
    __syncthreads();
    half8 af[2][4], bf[NT][4];
#pragma unroll
    for (int mt = 0; mt < 2; ++mt) {
      int row = wm * 64 + mt * 32 + l31;
#pragma unroll
      for (int kf = 0; kf < 4; ++kf)
        af[mt][kf] = *(const half8*)(a_lds + row * 64 + ((kf * 2 + hw) ^ (row & 7)) * 8);
    }
#pragma unroll
    for (int nt = 0; nt < NT; ++nt) {
      int row = wn * (BN / 2) + nt * 32 + l31;
#pragma unroll
      for (int kf = 0; kf < 4; ++kf)
        bf[nt][kf] = *(const half8*)(b_lds + row * 64 + ((kf * 2 + hw) ^ (row & 7)) * 8);
    }
#pragma unroll
    for (int kf = 0; kf < 4; ++kf)
#pragma unroll
      for (int mt = 0; mt < 2; ++mt)
#pragma unroll
        for (int nt = 0; nt < NT; ++nt)
          acc[mt][nt] =
              __builtin_amdgcn_mfma_f32_32x32x16_f16(af[mt][kf], bf[nt][kf], acc[mt][nt], 0, 0, 0);
    __syncthreads();
  }

  // C/D 32x32 mapping: col = lane&31, row = (r&3) + 8*(r>>2) + 4*(lane>>5)
  if (MODE == 0) {
    const int which = col0 >> 10;
#pragma unroll
    for (int mt = 0; mt < 2; ++mt)
#pragma unroll
      for (int nt = 0; nt < NT; ++nt) {
        int growb = row0 + wm * 64 + mt * 32;
        int gcol = col0 + wn * (BN / 2) + nt * 32 + l31;
        int hc = gcol & 1023, h = hc >> 6, d = hc & 63;
        if (which == 2) {
#pragma unroll
          for (int rq = 0; rq < 4; ++rq) {
            int grow = growb + 8 * rq + 4 * hw;
            int b = grow >> 11, n0 = grow & 2047;
            int bh = b * NH + h;
            half4_t h4;
            h4.x = (half_t)acc[mt][nt][rq * 4 + 0];
            h4.y = (half_t)acc[mt][nt][rq * 4 + 1];
            h4.z = (half_t)acc[mt][nt][rq * 4 + 2];
            h4.w = (half_t)acc[mt][nt][rq * 4 + 3];
            *(half4_t*)(vT16 + ((size_t)bh * DH + d) * SEQ + n0) = h4;
          }
        } else {
#pragma unroll
          for (int r = 0; r < 16; ++r) {
            int grow = growb + (r & 3) + 8 * (r >> 2) + 4 * hw;
            int b = grow >> 11, n = grow & 2047;
            int bh = b * NH + h;
            float v = acc[mt][nt][r];
            if (which == 0)
              q16[((size_t)bh * SEQ + n) * DH + d] =
                  (half_t)(v * 0.1803368801111204f);  // fold SCALE * log2(e)
            else
              k16[((size_t)bh * SEQ + n) * DH + d] = (half_t)v;
          }
        }
      }
  } else {
#pragma unroll
    for (int mt = 0; mt < 2; ++mt)
#pragma unroll
      for (int nt = 0; nt < NT; ++nt) {
        int growb = row0 + wm * 64 + mt * 32;
        int gcol = col0 + wn * (BN / 2) + nt * 32 + l31;
#pragma unroll
        for (int r = 0; r < 16; ++r) {
          int grow = growb + (r & 3) + 8 * (r >> 2) + 4 * hw;
          outp[(size_t)grow * DIM_ + gcol] = acc[mt][nt][r];
        }
      }
  }
}

// Flash attention pass 1, all-32x32x16. Block = 4 waves x 32 q = 128 q-rows;
// j-slice SEQ/NJS. NJS=2 -> 1024 blocks = exactly 4 blocks/CU; paired with
// launch_bounds(256,4) (128-reg cap -> 4 waves/SIMD) to lift residency.
// S^T = mfma(K,Q): lane l31 = q. PV A-frags built in NATURAL k-order via
// v_cvt_pkrtz + v_permlane32_swap; V B-frags are natural b128 reads.
__global__ __launch_bounds__(256, 4) void attn_p1(const half_t* __restrict__ q16,
                                                  const half_t* __restrict__ k16,
                                                  const half_t* __restrict__ vT16,
                                                  half_t* __restrict__ opart,
                                                  float* __restrict__ psums) {
  __shared__ __align__(16) half_t k_lds[2][64 * 64];  // [j][d]
  __shared__ __align__(16) half_t v_lds[2][64 * 64];  // vT: [d][j]

  const int t = threadIdx.x;
  const int wave = t >> 6, lane = t & 63;
  const int l31 = lane & 31, hw = lane >> 5;
  const int blk = blockIdx.x;
  const int js = blk & (NJS - 1), qt = (blk / NJS) & 15, bh = blk / (NJS * 16);
  const half_t* qp = q16 + (size_t)bh * SEQ * DH;
  const half_t* kp = k16 + (size_t)bh * SEQ * DH;
  const half_t* vp = vT16 + (size_t)bh * DH * SEQ;
  const int q0w = qt * 128 + wave * 32;
  const int jbase = js * (SEQ / NJS);
  constexpr int NJT = (SEQ / NJS) / 64;  // 16

  // staging offsets: 512 segs of 16B (64 rows x 8 chunks), chunk XOR row&7
  const int s0 = t, s1 = t + 256;
  const int r0_ = s0 >> 3, c0_ = (s0 & 7) ^ (r0_ & 7);
  const int r1_ = s1 >> 3, c1_ = (s1 & 7) ^ (r1_ & 7);

  // Q fragments, B-operand 32x32x16: col = l31 = q, k = kf*16 + hw*8 + i
  half8 qf[4];
#pragma unroll
  for (int kf = 0; kf < 4; ++kf)
    qf[kf] = *(const half8*)(qp + (size_t)(q0w + l31) * DH + kf * 16 + hw * 8);

  floatx16 o[2];  // [d-tile]; C/D: col=l31=d, row=(r&3)+8(r>>2)+4hw = q
#pragma unroll
  for (int i = 0; i < 2; ++i)
#pragma unroll
    for (int r = 0; r < 16; ++r) o[i][r] = 0.f;
  float psum = 0.f;

  // prologue: stage tile jbase into buffer 0
  gl2lds16(kp + (size_t)(jbase + r0_) * DH + c0_ * 8, &k_lds[0][(wave * 64) * 8]);
  gl2lds16(vp + (size_t)r0_ * SEQ + jbase + c0_ * 8, &v_lds[0][(wave * 64) * 8]);
  gl2lds16(kp + (size_t)(jbase + r1_) * DH + c1_ * 8, &k_lds[0][(wave * 64 + 256) * 8]);
  gl2lds16(vp + (size_t)r1_ * SEQ + jbase + c1_ * 8, &v_lds[0][(wave * 64 + 256) * 8]);

  int cur = 0;
  for (int jt = 0; jt < NJT; ++jt) {
    __syncthreads();  // publishes buf[cur], protects buf[cur^1]

    if (jt + 1 < NJT) {
      const int j0 = jbase + (jt + 1) * 64, nb = cur ^ 1;
      gl2lds16(kp + (size_t)(j0 + r0_) * DH + c0_ * 8, &k_lds[nb][(wave * 64) * 8]);
      gl2lds16(vp + (size_t)r0_ * SEQ + j0 + c0_ * 8, &v_lds[nb][(wave * 64) * 8]);
      gl2lds16(kp + (size_t)(j0 + r1_) * DH + c1_ * 8, &k_lds[nb][(wave * 64 + 256) * 8]);
      gl2lds16(vp + (size_t)r1_ * SEQ + j0 + c1_ * 8, &v_lds[nb][(wave * 64 + 256) * 8]);
    }

    const half_t* kl = k_lds[cur];
    const half_t* vl = v_lds[cur];

    // S^T[j 64][q 32]: A = K (m=j, 2 tiles), B = Q. 8 MFMAs of 32x32x16.
    floatx16 st[2];
#pragma unroll
    for (int m = 0; m < 2; ++m)
#pragma unroll
      for (int r = 0; r < 16; ++r) st[m][r] = 0.f;
    __builtin_amdgcn_s_setprio(1);
#pragma unroll
    for (int kf = 0; kf < 4; ++kf)
#pragma unroll
      for (int m = 0; m < 2; ++m) {
        int row = m * 32 + l31;  // j
        half8 kb = *(const half8*)(kl + row * 64 + ((kf * 2 + hw) ^ (row & 7)) * 8);
        st[m] = __builtin_amdgcn_mfma_f32_32x32x16_f16(kb, qf[kf], st[m], 0, 0, 0);
      }
    __builtin_amdgcn_s_setprio(0);

    // exp2 -> psum + natural-k PV A-frags (cvt_pkrtz + permlane32_swap)
    half8 pa[4];
#pragma unroll
    for (int ks = 0; ks < 4; ++ks) {
      const int m = ks >> 1, rb = (ks & 1) * 8;
      float p0 = fexp2(st[m][rb + 0]);
      float p1 = fexp2(st[m][rb + 1]);
      float p2 = fexp2(st[m][rb + 2]);
      float p3 = fexp2(st[m][rb + 3]);
      float p4 = fexp2(st[m][rb + 4]);
      float p5 = fexp2(st[m][rb + 5]);
      float p6 = fexp2(st[m][rb + 6]);
      float p7 = fexp2(st[m][rb + 7]);
      psum += ((p0 + p1) + (p2 + p3)) + ((p4 + p5) + (p6 + p7));
      unsigned uA = cvtpk_u32(p0, p1);
      unsigned uB = cvtpk_u32(p2, p3);
      unsigned uC = cvtpk_u32(p4, p5);
      unsigned uD = cvtpk_u32(p6, p7);
#if __has_builtin(__builtin_amdgcn_permlane32_swap)
      uint2v sAC = __builtin_bit_cast(uint2v, __builtin_amdgcn_permlane32_swap(uA, uC, false, false));
      uint2v sBD = __builtin_bit_cast(uint2v, __builtin_amdgcn_permlane32_swap(uB, uD, false, false));
      uint4v u;
      u.x = sAC.x; u.y = sBD.x; u.z = sAC.y; u.w = sBD.y;
#else
      unsigned xA = (unsigned)__shfl_xor((int)uA, 32, 64);
      unsigned xB = (unsigned)__shfl_xor((int)uB, 32, 64);
      unsigned xC = (unsigned)__shfl_xor((int)uC, 32, 64);
      unsigned xD = (unsigned)__shfl_xor((int)uD, 32, 64);
      uint4v u;
      u.x = hw ? xC : uA;
      u.y = hw ? xD : uB;
      u.z = hw ? uC : xA;
      u.w = hw ? uD : xB;
#endif
      pa[ks] = __builtin_bit_cast(half8, u);
    }

    // O[q 32][d 64] += P@V. 8 MFMAs; V B-frag natural b128:
    // lane l31 = d-col (vT row), k = j = ks*16 + hw*8 + i -> chunk ks*2+hw.
    __builtin_amdgcn_s_setprio(1);
#pragma unroll
    for (int ks = 0; ks < 4; ++ks)
#pragma unroll
      for (int dt = 0; dt < 2; ++dt) {
        int row = dt * 32 + l31;  // d
        half8 vb = *(const half8*)(vl + row * 64 + ((ks * 2 + hw) ^ (row & 7)) * 8);
        o[dt] = __builtin_amdgcn_mfma_f32_32x32x16_f16(pa[ks], vb, o[dt], 0, 0, 0);
      }
    __builtin_amdgcn_s_setprio(0);
    cur ^= 1;
  }

  // psum: lane holds sum over its half's j for q = q0w + l31
  psum += __shfl_xor(psum, 32, 64);
  if (hw == 0) psums[((size_t)(js * 32 + bh)) * SEQ + q0w + l31] = psum;

  // unnormalized O -> fp16 partials; q = q0w + (r&3)+8(r>>2)+4hw, d = dt*32+l31
#pragma unroll
  for (int dt = 0; dt < 2; ++dt)
#pragma unroll
    for (int r = 0; r < 16; ++r) {
      int n = q0w + (r & 3) + 8 * (r >> 2) + 4 * hw;
      opart[((size_t)(js * 32 + bh) * SEQ + n) * DH + dt * 32 + l31] = (half_t)o[dt][r];
    }
}

// combine: out = (sum_js O_js) * softmax(head_w)[h] / (sum_js ps_js), fp16 attn16
__global__ __launch_bounds__(256) void combine(const half_t* __restrict__ opart,
                                               const float* __restrict__ psums,
                                               const float* __restrict__ head_w,
                                               half_t* __restrict__ attn16) {
  int idx = blockIdx.x * blockDim.x + threadIdx.x;  // 1M threads, 4 d each
  int d4 = idx & 15, n = (idx >> 4) & 2047, bh = idx >> 15;
  int h = bh & 15, b = bh >> 4;
  const size_t jstr = (size_t)32 * SEQ * DH;
  size_t off = ((size_t)bh * SEQ + n) * DH + d4 * 4;

  float sx = 0.f, sy = 0.f, sz = 0.f, sw2 = 0.f, ps = 0.f;
#pragma unroll
  for (int js = 0; js < NJS; ++js) {
    half4_t ov = *(const half4_t*)(opart + js * jstr + off);
    sx += (float)ov.x; sy += (float)ov.y; sz += (float)ov.z; sw2 += (float)ov.w;
    ps += psums[(size_t)js * 32 * SEQ + (size_t)bh * SEQ + n];
  }

  float mw = head_w[0];
#pragma unroll
  for (int i = 1; i < NH; ++i) mw = fmaxf(mw, head_w[i]);
  float sw = 0.f;
#pragma unroll
  for (int i = 0; i < NH; ++i) sw += __expf(head_w[i] - mw);
  float hwv = __expf(head_w[h] - mw) / sw;

  float scl = hwv / ps;
  half4_t r;
  r.x = (half_t)(sx * scl);
  r.y = (half_t)(sy * scl);
  r.z = (half_t)(sz * scl);
  r.w = (half_t)(sw2 * scl);
  *(half4_t*)(attn16 + ((size_t)(b * SEQ + n)) * DIM_ + h * DH + d4 * 4) = r;
}

extern "C" void kernel_launch(void* const* d_in, const int* in_sizes, int n_in,
                              void* d_out, int out_size, void* d_ws, size_t ws_size,
                              hipStream_t stream) {
  const float* x = (const float*)d_in[0];
  const float* w_qkv = (const float*)d_in[1];
  const float* w_proj = (const float*)d_in[2];
  const float* head_w = (const float*)d_in[3];
  float* out = (float*)d_out;

  half_t* x16 = (half_t*)d_ws;                          // 4096*1024
  half_t* wq16 = x16 + (size_t)ROWS * DIM_;             // 3072*1024
  half_t* wp16 = wq16 + (size_t)3 * DIM_ * DIM_;        // 1024*1024
  half_t* q16 = wp16 + (size_t)DIM_ * DIM_;             // [B,H,N,Dh] (scaled by 0.125*log2e)
  half_t* k16 = q16 + (size_t)ROWS * DIM_;              // [B,H,N,Dh]
  half_t* vT16 = k16 + (size_t)ROWS * DIM_;             // [B,H,Dh,N]
  half_t* attn16 = vT16 + (size_t)ROWS * DIM_;          // [B*N, DIM]
  half_t* opart = attn16 + (size_t)ROWS * DIM_;         // [NJS][32][2048][64] fp16
  float* psums = (float*)(opart + (size_t)NJS * 32 * SEQ * DH);  // [NJS][32][2048] f32

  const int nx = ROWS * DIM_ / 4, nq = 3 * DIM_ * DIM_ / 4, np = DIM_ * DIM_ / 4;
  convert_all<<<(nx + nq + np) / 256, 256, 0, stream>>>((const float4*)x, (const float4*)w_qkv,
                                                        (const float4*)w_proj, (half4_t*)x16,
                                                        nx, nq, np);

  gemm32<0, 128><<<dim3(24, 32), 256, 0, stream>>>(x16, wq16, q16, k16, vT16, nullptr);
  attn_p1<<<32 * 16 * NJS, 256, 0, stream>>>(q16, k16, vT16, opart, psums);
  combine<<<(32 * SEQ * DH / 4) / 256, 256, 0, stream>>>(opart, psums, head_w, attn16);
  gemm32<1, 64><<<dim3(16, 32), 256, 0, stream>>>(attn16, wp16, nullptr, nullptr, nullptr, out);
}